// Round 1
// baseline (5611.442 us; speedup 1.0000x reference)
//
#include <hip/hip_runtime.h>
#include <hip/hip_bf16.h>
#include <math.h>

#define KNN 20

// ---------------------------------------------------------------- rowsq
template<int C>
__global__ void rowsq_kernel(const float* __restrict__ x, float* __restrict__ sq, int N) {
    int i = blockIdx.x * blockDim.x + threadIdx.x;
    if (i >= N) return;
    float s = 0.f;
    if constexpr (C == 64) {
        const float4* p = reinterpret_cast<const float4*>(x + (size_t)i * C);
#pragma unroll
        for (int c = 0; c < 16; ++c) {
            float4 v = p[c];
            s += v.x * v.x + v.y * v.y + v.z * v.z + v.w * v.w;
        }
    } else {
#pragma unroll
        for (int c = 0; c < C; ++c) { float v = x[(size_t)i * C + c]; s += v * v; }
    }
    sq[i] = s;
}

// ---------------------------------------------------------------- knn
// block = 256 threads = 4 points x 64 lanes (one wave per point).
// Per-lane register-resident sorted top-20 over strided candidates, then LDS
// tree merge of the 64 per-lane lists. Lexicographic (dist, idx) compare
// matches jax.lax.top_k tie-breaking (lowest index wins).
template<int C, int TILE, int ROWF>
__global__ __launch_bounds__(256) void knn_kernel(
    const float* __restrict__ x, const float* __restrict__ sq,
    int* __restrict__ nbrs, int N) {
    constexpr int TPP = 64;  // threads per point (== one wave)
    constexpr int M = 4;     // points per block
    constexpr int SMEM_TILE = TILE * ROWF + TILE;
    constexpr int SMEM_MERGE = 256 * KNN * 2;
    constexpr int SMEM = SMEM_TILE > SMEM_MERGE ? SMEM_TILE : SMEM_MERGE;
    __shared__ __align__(16) float smem[SMEM];

    float* xs = smem;                 // [TILE][ROWF]
    float* sqs = smem + TILE * ROWF;  // [TILE]

    const int tid = threadIdx.x;
    const int g = tid >> 6;   // point group
    const int l = tid & 63;   // lane
    const int i = blockIdx.x * M + g;

    // xi in registers
    float4 xi4[(C + 3) / 4];
    if constexpr (C == 64) {
        const float4* xp = reinterpret_cast<const float4*>(x + (size_t)i * C);
#pragma unroll
        for (int c4 = 0; c4 < 16; ++c4) xi4[c4] = xp[c4];
    } else {
        xi4[0].x = x[(size_t)i * 3 + 0];
        xi4[0].y = x[(size_t)i * 3 + 1];
        xi4[0].z = x[(size_t)i * 3 + 2];
        xi4[0].w = 0.f;
    }
    const float sqi = sq[i];

    float d[KNN]; int id[KNN];
#pragma unroll
    for (int t = 0; t < KNN; ++t) { d[t] = __builtin_inff(); id[t] = 0x7fffffff; }

    for (int t0 = 0; t0 < N; t0 += TILE) {
        // stage tile of x rows + sq
        if constexpr (C == 64) {
            for (int idx = tid; idx < TILE * 16; idx += 256) {
                int row = idx >> 4, c4 = idx & 15;
                reinterpret_cast<float4*>(xs + row * ROWF)[c4] =
                    reinterpret_cast<const float4*>(x + (size_t)(t0 + row) * C)[c4];
            }
        } else {
            for (int idx = tid; idx < TILE * C; idx += 256) {
                int row = idx / C, c = idx % C;
                xs[row * ROWF + c] = x[(size_t)(t0 + row) * C + c];
            }
        }
        for (int idx = tid; idx < TILE; idx += 256) sqs[idx] = sq[t0 + idx];
        __syncthreads();

#pragma unroll 1
        for (int jj = l; jj < TILE; jj += TPP) {
            int j = t0 + jj;
            float dot;
            if constexpr (C == 64) {
                const float4* rp = reinterpret_cast<const float4*>(xs + jj * ROWF);
                float s0 = 0.f, s1 = 0.f, s2 = 0.f, s3 = 0.f;
#pragma unroll
                for (int c4 = 0; c4 < 16; ++c4) {
                    float4 v = rp[c4];
                    s0 += xi4[c4].x * v.x; s1 += xi4[c4].y * v.y;
                    s2 += xi4[c4].z * v.z; s3 += xi4[c4].w * v.w;
                }
                dot = (s0 + s1) + (s2 + s3);
            } else {
                const float* rp = xs + jj * ROWF;
                dot = xi4[0].x * rp[0] + xi4[0].y * rp[1] + xi4[0].z * rp[2];
            }
            float dist = sqi + sqs[jj] - 2.f * dot;
            if (j != i) {
                bool ins = (dist < d[KNN - 1]) ||
                           (dist == d[KNN - 1] && j < id[KNN - 1]);
                if (ins) {
                    d[KNN - 1] = dist; id[KNN - 1] = j;
#pragma unroll
                    for (int t = KNN - 1; t >= 1; --t) {
                        bool sw = (d[t] < d[t - 1]) ||
                                  (d[t] == d[t - 1] && id[t] < id[t - 1]);
                        if (sw) {
                            float td = d[t]; d[t] = d[t - 1]; d[t - 1] = td;
                            int ti = id[t]; id[t] = id[t - 1]; id[t - 1] = ti;
                        }
                    }
                }
            }
        }
        __syncthreads();  // protects next tile overwrite AND merge reuse
    }

    // merge buffers alias the tile region (safe: synced above)
    float* md = smem;                      // [256][KNN]
    int* mi = (int*)(smem + 256 * KNN);    // [256][KNN]

#pragma unroll
    for (int t = 0; t < KNN; ++t) { md[tid * KNN + t] = d[t]; mi[tid * KNN + t] = id[t]; }
    __syncthreads();

    for (int s = TPP / 2; s >= 1; s >>= 1) {
        if (l < s) {
            int a = (g * TPP + l) * KNN, b = a + s * KNN;
            float od[KNN]; int oi[KNN];
            int pa = 0, pb = 0;
#pragma unroll
            for (int t = 0; t < KNN; ++t) {  // pa,pb <= 19 here: no OOB
                float da = md[a + pa], db = md[b + pb];
                int ia = mi[a + pa], ib = mi[b + pb];
                bool takeA = (da < db) || (da == db && ia <= ib);
                od[t] = takeA ? da : db;
                oi[t] = takeA ? ia : ib;
                pa += takeA ? 1 : 0; pb += takeA ? 0 : 1;
            }
#pragma unroll
            for (int t = 0; t < KNN; ++t) { md[a + t] = od[t]; mi[a + t] = oi[t]; }
        }
        __syncthreads();
    }
    if (l < KNN) nbrs[(size_t)i * KNN + l] = mi[g * TPP * KNN + l];
}

// ---------------------------------------------------------------- edgeconv
// h[f] = b[f] + sum_c xi[c]*(W[c][f]-W[C+c][f]) + sum_c xj[c]*W[C+c][f]
// out[i][f] = max_j relu(h)
template<int C>
__global__ __launch_bounds__(64) void edgeconv_kernel(
    const float* __restrict__ x, const int* __restrict__ nbrs,
    const float* __restrict__ w, const float* __restrict__ bias,
    float* __restrict__ out, int N) {
    constexpr int F = 64;
    __shared__ float Wl[2 * C * F];
    __shared__ float xi[C];
    __shared__ float xj[KNN * C];
    __shared__ int nb[KNN];
    const int f = threadIdx.x;
    const int i = blockIdx.x;

    for (int idx = f; idx < 2 * C * F; idx += 64) Wl[idx] = w[idx];
    if (f < KNN) nb[f] = nbrs[(size_t)i * KNN + f];
    if (f < C) xi[f] = x[(size_t)i * C + f];
    __syncthreads();
#pragma unroll 1
    for (int j = 0; j < KNN; ++j)
        if (f < C) xj[j * C + f] = x[(size_t)nb[j] * C + f];
    __syncthreads();

    float base = bias[f];
#pragma unroll
    for (int c = 0; c < C; ++c)
        base += xi[c] * (Wl[c * F + f] - Wl[(C + c) * F + f]);
    float maxv = 0.f;  // relu outputs >= 0, max of 20 of them >= 0
#pragma unroll 1
    for (int j = 0; j < KNN; ++j) {
        float acc = base;
#pragma unroll
        for (int c = 0; c < C; ++c) acc += xj[j * C + c] * Wl[(C + c) * F + f];
        maxv = fmaxf(maxv, acc);
    }
    out[(size_t)i * F + f] = maxv;
}

// ---------------------------------------------------------------- concat
__global__ void concat3_kernel(const float* __restrict__ a, const float* __restrict__ b,
                               const float* __restrict__ c, float* __restrict__ o, int N) {
    int t = blockIdx.x * blockDim.x + threadIdx.x;
    if (t >= N * 192) return;
    int r = t / 192, cc = t % 192;
    float v;
    if (cc < 64) v = a[(size_t)r * 64 + cc];
    else if (cc < 128) v = b[(size_t)r * 64 + cc - 64];
    else v = c[(size_t)r * 64 + cc - 128];
    o[t] = v;
}

// ---------------------------------------------------------------- GEMM
// C[M,N] = relu(A[M,K] @ B[K,N] + bias). 64x64 tiles, BK=16, 256 thr, 4x4/thr.
// Requires M%64==0, N%64==0, K%16==0.
template<bool RELU>
__global__ __launch_bounds__(256) void gemm_bias_relu(
    const float* __restrict__ A, const float* __restrict__ B,
    const float* __restrict__ bias, float* __restrict__ C,
    int M, int N, int K) {
    constexpr int BM = 64, BN = 64, BK = 16;
    __shared__ float As[BK][BM + 1];
    __shared__ float Bs[BK][BN + 1];
    const int tid = threadIdx.x;
    const int tx = tid & 15, ty = tid >> 4;
    const int m0 = blockIdx.y * BM, n0 = blockIdx.x * BN;
    float acc[4][4] = {};

    for (int k0 = 0; k0 < K; k0 += BK) {
        for (int idx = tid; idx < BM * BK; idx += 256) {
            int r = idx >> 4, c = idx & 15;
            As[c][r] = A[(size_t)(m0 + r) * K + k0 + c];
        }
        for (int idx = tid; idx < BK * BN; idx += 256) {
            int r = idx >> 6, c = idx & 63;
            Bs[r][c] = B[(size_t)(k0 + r) * N + n0 + c];
        }
        __syncthreads();
#pragma unroll
        for (int kk = 0; kk < BK; ++kk) {
            float a[4], b[4];
#pragma unroll
            for (int u = 0; u < 4; ++u) a[u] = As[kk][ty + 16 * u];
#pragma unroll
            for (int v = 0; v < 4; ++v) b[v] = Bs[kk][tx + 16 * v];
#pragma unroll
            for (int u = 0; u < 4; ++u)
#pragma unroll
                for (int v = 0; v < 4; ++v) acc[u][v] += a[u] * b[v];
        }
        __syncthreads();
    }
#pragma unroll
    for (int u = 0; u < 4; ++u) {
        int m = m0 + ty + 16 * u;
#pragma unroll
        for (int v = 0; v < 4; ++v) {
            int n = n0 + tx + 16 * v;
            float val = acc[u][v] + bias[n];
            if (RELU) val = fmaxf(val, 0.f);
            C[(size_t)m * N + n] = val;
        }
    }
}

// ---------------------------------------------------------------- last layer + log_softmax
// out[r] = log_softmax(A[r,0:128] @ W[128,13] + b)
__global__ __launch_bounds__(256) void last_layer_kernel(
    const float* __restrict__ A, const float* __restrict__ W,
    const float* __restrict__ b, float* __restrict__ out, int N) {
    constexpr int KD = 128, NC = 13;
    __shared__ float ws[KD * NC];
    __shared__ float bs[NC];
    const int tid = threadIdx.x;
    for (int idx = tid; idx < KD * NC; idx += 256) ws[idx] = W[idx];
    if (tid < NC) bs[tid] = b[tid];
    __syncthreads();
    int r = blockIdx.x * 256 + tid;
    if (r >= N) return;
    float acc[NC];
#pragma unroll
    for (int f = 0; f < NC; ++f) acc[f] = bs[f];
    const float4* row = reinterpret_cast<const float4*>(A + (size_t)r * KD);
#pragma unroll 4
    for (int c4 = 0; c4 < KD / 4; ++c4) {
        float4 v = row[c4];
#pragma unroll
        for (int f = 0; f < NC; ++f) acc[f] += v.x * ws[(c4 * 4 + 0) * NC + f];
#pragma unroll
        for (int f = 0; f < NC; ++f) acc[f] += v.y * ws[(c4 * 4 + 1) * NC + f];
#pragma unroll
        for (int f = 0; f < NC; ++f) acc[f] += v.z * ws[(c4 * 4 + 2) * NC + f];
#pragma unroll
        for (int f = 0; f < NC; ++f) acc[f] += v.w * ws[(c4 * 4 + 3) * NC + f];
    }
    float m = acc[0];
#pragma unroll
    for (int f = 1; f < NC; ++f) m = fmaxf(m, acc[f]);
    float s = 0.f;
#pragma unroll
    for (int f = 0; f < NC; ++f) s += expf(acc[f] - m);
    float ls = logf(s);
#pragma unroll
    for (int f = 0; f < NC; ++f) out[(size_t)r * NC + f] = acc[f] - m - ls;
}

// ---------------------------------------------------------------- launch
extern "C" void kernel_launch(void* const* d_in, const int* in_sizes, int n_in,
                              void* d_out, int out_size, void* d_ws, size_t ws_size,
                              hipStream_t stream) {
    const float* x   = (const float*)d_in[0];
    const float* w1  = (const float*)d_in[1];
    const float* b1  = (const float*)d_in[2];
    const float* w2  = (const float*)d_in[3];
    const float* b2  = (const float*)d_in[4];
    const float* w3  = (const float*)d_in[5];
    const float* b3  = (const float*)d_in[6];
    const float* wl1 = (const float*)d_in[7];
    const float* bl1 = (const float*)d_in[8];
    const float* wm1 = (const float*)d_in[9];
    const float* bm1 = (const float*)d_in[10];
    const float* wm2 = (const float*)d_in[11];
    const float* bm2 = (const float*)d_in[12];
    const float* wm3 = (const float*)d_in[13];
    const float* bm3 = (const float*)d_in[14];
    float* out = (float*)d_out;

    const int N = in_sizes[0] / 3;  // 8192

    float* ws = (float*)d_ws;
    size_t off = 0;
    auto alloc = [&](size_t n) { float* p = ws + off; off += n; return p; };
    float* sq  = alloc(N);
    int*   nbr = (int*)alloc((size_t)N * KNN);
    float* x1  = alloc((size_t)N * 64);
    float* x2  = alloc((size_t)N * 64);
    float* x3  = alloc((size_t)N * 64);
    float* cat = alloc((size_t)N * 192);
    float* a1  = alloc((size_t)N * 1024);
    float* a2  = alloc((size_t)N * 256);
    float* a3  = alloc((size_t)N * 128);

    // stage 1 (C=3)
    rowsq_kernel<3><<<N / 256, 256, 0, stream>>>(x, sq, N);
    knn_kernel<3, 256, 5><<<N / 4, 256, 0, stream>>>(x, sq, nbr, N);
    edgeconv_kernel<3><<<N, 64, 0, stream>>>(x, nbr, w1, b1, x1, N);
    // stage 2 (C=64)
    rowsq_kernel<64><<<N / 256, 256, 0, stream>>>(x1, sq, N);
    knn_kernel<64, 128, 68><<<N / 4, 256, 0, stream>>>(x1, sq, nbr, N);
    edgeconv_kernel<64><<<N, 64, 0, stream>>>(x1, nbr, w2, b2, x2, N);
    // stage 3 (C=64)
    rowsq_kernel<64><<<N / 256, 256, 0, stream>>>(x2, sq, N);
    knn_kernel<64, 128, 68><<<N / 4, 256, 0, stream>>>(x2, sq, nbr, N);
    edgeconv_kernel<64><<<N, 64, 0, stream>>>(x2, nbr, w3, b3, x3, N);
    // MLP head
    concat3_kernel<<<(N * 192 + 255) / 256, 256, 0, stream>>>(x1, x2, x3, cat, N);
    gemm_bias_relu<true><<<dim3(1024 / 64, N / 64), 256, 0, stream>>>(cat, wl1, bl1, a1, N, 1024, 192);
    gemm_bias_relu<true><<<dim3(256 / 64, N / 64), 256, 0, stream>>>(a1, wm1, bm1, a2, N, 256, 1024);
    gemm_bias_relu<true><<<dim3(128 / 64, N / 64), 256, 0, stream>>>(a2, wm2, bm2, a3, N, 128, 256);
    last_layer_kernel<<<(N + 255) / 256, 256, 0, stream>>>(a3, wm3, bm3, out, N);
}

// Round 2
// 4066.027 us; speedup vs baseline: 1.3801x; 1.3801x over previous
//
#include <hip/hip_runtime.h>
#include <hip/hip_bf16.h>
#include <math.h>

#define KNN 20
#define NSLICE 32   // candidate slices per point for knn_part

// ---------------------------------------------------------------- rowsq
template<int C>
__global__ void rowsq_kernel(const float* __restrict__ x, float* __restrict__ sq, int N) {
    int i = blockIdx.x * blockDim.x + threadIdx.x;
    if (i >= N) return;
    float s = 0.f;
    if constexpr (C == 64) {
        const float4* p = reinterpret_cast<const float4*>(x + (size_t)i * C);
#pragma unroll
        for (int c = 0; c < 16; ++c) {
            float4 v = p[c];
            s += v.x * v.x + v.y * v.y + v.z * v.z + v.w * v.w;
        }
    } else {
#pragma unroll
        for (int c = 0; c < C; ++c) { float v = x[(size_t)i * C + c]; s += v * v; }
    }
    sq[i] = s;
}

// ---------------------------------------------------------------- knn part
// Transposed mapping: each LANE owns one point (xi in registers); the wave
// iterates candidates j sequentially (wave-uniform -> scalar s_load of the
// candidate row, zero LDS). Each wave handles one slice of S=N/NSLICE
// candidates, keeping a per-lane sorted top-20 (lex (dist, idx) order ==
// jax.lax.top_k tie-break). Partial lists merged by knn_merge_kernel.
template<int C, int MINW>
__global__ __launch_bounds__(256, MINW) void knn_part_kernel(
    const float* __restrict__ x, const float* __restrict__ sq,
    float* __restrict__ pd, int* __restrict__ pi, int N) {
    const int tid = threadIdx.x;
    const int wave = tid >> 6, l = tid & 63;
    const int g = blockIdx.x;                  // point group (64 points)
    const int s = blockIdx.y * 4 + wave;       // slice id
    const int i = g * 64 + l;                  // my point
    const int S = N / NSLICE;
    const int j0 = s * S;

    float xi[C];
#pragma unroll
    for (int c = 0; c < C; ++c) xi[c] = x[(size_t)i * C + c];
    const float sqi = sq[i];

    float d[KNN]; int id[KNN];
#pragma unroll
    for (int t = 0; t < KNN; ++t) { d[t] = __builtin_inff(); id[t] = 0x7fffffff; }

#pragma unroll 2
    for (int j = j0; j < j0 + S; ++j) {
        const float* __restrict__ xr = x + (size_t)j * C;   // wave-uniform
        float dist;
        if constexpr (C == 64) {
            float s0 = 0.f, s1 = 0.f, s2 = 0.f, s3 = 0.f;
#pragma unroll
            for (int c = 0; c < C; c += 4) {
                s0 += xi[c + 0] * xr[c + 0];
                s1 += xi[c + 1] * xr[c + 1];
                s2 += xi[c + 2] * xr[c + 2];
                s3 += xi[c + 3] * xr[c + 3];
            }
            dist = sqi + sq[j] - 2.f * ((s0 + s1) + (s2 + s3));
        } else {
            float dot = xi[0] * xr[0] + xi[1] * xr[1] + xi[2] * xr[2];
            dist = sqi + sq[j] - 2.f * dot;
        }
        bool ins = (j != i) && ((dist < d[KNN - 1]) ||
                                (dist == d[KNN - 1] && j < id[KNN - 1]));
        if (ins) {
            d[KNN - 1] = dist; id[KNN - 1] = j;
#pragma unroll
            for (int t = KNN - 1; t >= 1; --t) {
                bool sw = (d[t] < d[t - 1]) ||
                          (d[t] == d[t - 1] && id[t] < id[t - 1]);
                if (sw) {
                    float td = d[t]; d[t] = d[t - 1]; d[t - 1] = td;
                    int ti = id[t]; id[t] = id[t - 1]; id[t - 1] = ti;
                }
            }
        }
    }

    const size_t base = ((size_t)i * NSLICE + s) * KNN;
#pragma unroll
    for (int t = 0; t < KNN; ++t) { pd[base + t] = d[t]; pi[base + t] = id[t]; }
}

// ---------------------------------------------------------------- knn merge
// Per point: NSLICE sorted 20-lists -> tree merge -> top-20 indices.
// Block = 256 threads = 8 points x 32 list-threads.
__global__ __launch_bounds__(256) void knn_merge_kernel(
    const float* __restrict__ pd, const int* __restrict__ pi,
    int* __restrict__ nbrs, int N) {
    __shared__ float md[8 * NSLICE * KNN];
    __shared__ int   mi[8 * NSLICE * KNN];
    const int tid = threadIdx.x;
    const int pl = tid >> 5, l = tid & 31;
    const int p = blockIdx.x * 8 + pl;
    const int lb = pl * NSLICE * KNN;

    const size_t src = ((size_t)p * NSLICE + l) * KNN;
#pragma unroll
    for (int t = 0; t < KNN; ++t) {
        md[lb + l * KNN + t] = pd[src + t];
        mi[lb + l * KNN + t] = pi[src + t];
    }
    __syncthreads();

    for (int s = NSLICE / 2; s >= 1; s >>= 1) {
        if (l < s) {
            int a = lb + l * KNN, b = a + s * KNN;
            float od[KNN]; int oi[KNN];
            int pa = 0, pb = 0;
#pragma unroll
            for (int t = 0; t < KNN; ++t) {   // pa,pb <= 19 at access: no OOB
                float da = md[a + pa], db = md[b + pb];
                int ia = mi[a + pa], ib = mi[b + pb];
                bool takeA = (da < db) || (da == db && ia <= ib);
                od[t] = takeA ? da : db;
                oi[t] = takeA ? ia : ib;
                pa += takeA ? 1 : 0; pb += takeA ? 0 : 1;
            }
#pragma unroll
            for (int t = 0; t < KNN; ++t) { md[a + t] = od[t]; mi[a + t] = oi[t]; }
        }
        __syncthreads();
    }
    if (l < KNN) nbrs[(size_t)p * KNN + l] = mi[lb + l];
}

// ---------------------------------------------------------------- edgeconv (factored)
// e_ij = W1^T xi + W2^T (xj - xi) + b = (W1-W2)^T xi + b  +  W2^T xj
// prep_w builds WW[C][128]: cols 0..63 = W1-W2, cols 64..127 = W2; bb = {b, 0}.
template<int C>
__global__ void prep_w_kernel(const float* __restrict__ w, const float* __restrict__ b,
                              float* __restrict__ WW, float* __restrict__ bb) {
    int t = blockIdx.x * blockDim.x + threadIdx.x;
    if (t < 128) bb[t] = (t < 64) ? b[t] : 0.f;
    if (t >= C * 128) return;
    int c = t >> 7, f = t & 127;
    WW[t] = (f < 64) ? (w[c * 64 + f] - w[(C + c) * 64 + f]) : w[(C + c) * 64 + (f - 64)];
}

// AB[N,128] = x[N,C] @ WW[C,128] + bb.  Block = 128 threads, 32 rows/block.
template<int C>
__global__ __launch_bounds__(128) void ec_gemm_kernel(
    const float* __restrict__ x, const float* __restrict__ WW,
    const float* __restrict__ bb, float* __restrict__ AB, int N) {
    __shared__ float Ws[C * 128];
    __shared__ float xs[32 * C];
    const int tid = threadIdx.x;
    const int r0 = blockIdx.x * 32;
    for (int idx = tid; idx < C * 128; idx += 128) Ws[idx] = WW[idx];
    for (int idx = tid; idx < 32 * C; idx += 128) xs[idx] = x[(size_t)r0 * C + idx];
    __syncthreads();
    const float bias = bb[tid];
#pragma unroll 1
    for (int r = 0; r < 32; ++r) {
        float acc = bias;
#pragma unroll
        for (int c = 0; c < C; ++c) acc = fmaf(xs[r * C + c], Ws[c * 128 + tid], acc);
        AB[(size_t)(r0 + r) * 128 + tid] = acc;
    }
}

// out[i][f] = relu(A[i][f] + max_j B[nbr(i,j)][f]).  Wave per point, lane = feature.
__global__ __launch_bounds__(256) void ec_max_kernel(
    const float* __restrict__ AB, const int* __restrict__ nbrs,
    float* __restrict__ out, int N) {
    const int tid = threadIdx.x;
    const int w = tid >> 6, f = tid & 63;
    const int i = blockIdx.x * 4 + w;
    const float a = AB[(size_t)i * 128 + f];
    const int* nb = nbrs + (size_t)i * KNN;
    float m = -3.4e38f;
#pragma unroll
    for (int j = 0; j < KNN; ++j) {
        int n = nb[j];                          // wave-uniform -> scalar load
        m = fmaxf(m, AB[(size_t)n * 128 + 64 + f]);
    }
    out[(size_t)i * 64 + f] = fmaxf(a + m, 0.f);
}

// ---------------------------------------------------------------- concat
__global__ void concat3_kernel(const float* __restrict__ a, const float* __restrict__ b,
                               const float* __restrict__ c, float* __restrict__ o, int N) {
    int t = blockIdx.x * blockDim.x + threadIdx.x;
    if (t >= N * 192) return;
    int r = t / 192, cc = t % 192;
    float v;
    if (cc < 64) v = a[(size_t)r * 64 + cc];
    else if (cc < 128) v = b[(size_t)r * 64 + cc - 64];
    else v = c[(size_t)r * 64 + cc - 128];
    o[t] = v;
}

// ---------------------------------------------------------------- GEMM
// C[M,N] = relu(A[M,K] @ B[K,N] + bias). 64x64 tiles, BK=16, 256 thr, 4x4/thr.
template<bool RELU>
__global__ __launch_bounds__(256) void gemm_bias_relu(
    const float* __restrict__ A, const float* __restrict__ B,
    const float* __restrict__ bias, float* __restrict__ C,
    int M, int N, int K) {
    constexpr int BM = 64, BN = 64, BK = 16;
    __shared__ float As[BK][BM + 1];
    __shared__ float Bs[BK][BN + 1];
    const int tid = threadIdx.x;
    const int tx = tid & 15, ty = tid >> 4;
    const int m0 = blockIdx.y * BM, n0 = blockIdx.x * BN;
    float acc[4][4] = {};

    for (int k0 = 0; k0 < K; k0 += BK) {
        for (int idx = tid; idx < BM * BK; idx += 256) {
            int r = idx >> 4, c = idx & 15;
            As[c][r] = A[(size_t)(m0 + r) * K + k0 + c];
        }
        for (int idx = tid; idx < BK * BN; idx += 256) {
            int r = idx >> 6, c = idx & 63;
            Bs[r][c] = B[(size_t)(k0 + r) * N + n0 + c];
        }
        __syncthreads();
#pragma unroll
        for (int kk = 0; kk < BK; ++kk) {
            float a[4], b[4];
#pragma unroll
            for (int u = 0; u < 4; ++u) a[u] = As[kk][ty + 16 * u];
#pragma unroll
            for (int v = 0; v < 4; ++v) b[v] = Bs[kk][tx + 16 * v];
#pragma unroll
            for (int u = 0; u < 4; ++u)
#pragma unroll
                for (int v = 0; v < 4; ++v) acc[u][v] += a[u] * b[v];
        }
        __syncthreads();
    }
#pragma unroll
    for (int u = 0; u < 4; ++u) {
        int m = m0 + ty + 16 * u;
#pragma unroll
        for (int v = 0; v < 4; ++v) {
            int n = n0 + tx + 16 * v;
            float val = acc[u][v] + bias[n];
            if (RELU) val = fmaxf(val, 0.f);
            C[(size_t)m * N + n] = val;
        }
    }
}

// ---------------------------------------------------------------- last layer + log_softmax
__global__ __launch_bounds__(256) void last_layer_kernel(
    const float* __restrict__ A, const float* __restrict__ W,
    const float* __restrict__ b, float* __restrict__ out, int N) {
    constexpr int KD = 128, NC = 13;
    __shared__ float ws[KD * NC];
    __shared__ float bs[NC];
    const int tid = threadIdx.x;
    for (int idx = tid; idx < KD * NC; idx += 256) ws[idx] = W[idx];
    if (tid < NC) bs[tid] = b[tid];
    __syncthreads();
    int r = blockIdx.x * 256 + tid;
    if (r >= N) return;
    float acc[NC];
#pragma unroll
    for (int f = 0; f < NC; ++f) acc[f] = bs[f];
    const float4* row = reinterpret_cast<const float4*>(A + (size_t)r * KD);
#pragma unroll 4
    for (int c4 = 0; c4 < KD / 4; ++c4) {
        float4 v = row[c4];
#pragma unroll
        for (int f = 0; f < NC; ++f) acc[f] += v.x * ws[(c4 * 4 + 0) * NC + f];
#pragma unroll
        for (int f = 0; f < NC; ++f) acc[f] += v.y * ws[(c4 * 4 + 1) * NC + f];
#pragma unroll
        for (int f = 0; f < NC; ++f) acc[f] += v.z * ws[(c4 * 4 + 2) * NC + f];
#pragma unroll
        for (int f = 0; f < NC; ++f) acc[f] += v.w * ws[(c4 * 4 + 3) * NC + f];
    }
    float m = acc[0];
#pragma unroll
    for (int f = 1; f < NC; ++f) m = fmaxf(m, acc[f]);
    float s = 0.f;
#pragma unroll
    for (int f = 0; f < NC; ++f) s += expf(acc[f] - m);
    float ls = logf(s);
#pragma unroll
    for (int f = 0; f < NC; ++f) out[(size_t)r * NC + f] = acc[f] - m - ls;
}

// ---------------------------------------------------------------- launch
extern "C" void kernel_launch(void* const* d_in, const int* in_sizes, int n_in,
                              void* d_out, int out_size, void* d_ws, size_t ws_size,
                              hipStream_t stream) {
    const float* x   = (const float*)d_in[0];
    const float* w1  = (const float*)d_in[1];
    const float* b1  = (const float*)d_in[2];
    const float* w2  = (const float*)d_in[3];
    const float* b2  = (const float*)d_in[4];
    const float* w3  = (const float*)d_in[5];
    const float* b3  = (const float*)d_in[6];
    const float* wl1 = (const float*)d_in[7];
    const float* bl1 = (const float*)d_in[8];
    const float* wm1 = (const float*)d_in[9];
    const float* bm1 = (const float*)d_in[10];
    const float* wm2 = (const float*)d_in[11];
    const float* bm2 = (const float*)d_in[12];
    const float* wm3 = (const float*)d_in[13];
    const float* bm3 = (const float*)d_in[14];
    float* out = (float*)d_out;

    const int N = in_sizes[0] / 3;  // 8192

    float* ws = (float*)d_ws;
    size_t off = 0;
    auto alloc = [&](size_t n) { float* p = ws + off; off += n; return p; };
    float* sq  = alloc(N);
    int*   nbr = (int*)alloc((size_t)N * KNN);
    float* x1  = alloc((size_t)N * 64);
    float* x2  = alloc((size_t)N * 64);
    float* x3  = alloc((size_t)N * 64);
    float* AB  = alloc((size_t)N * 128);
    float* WW  = alloc(64 * 128);
    float* bb  = alloc(128);
    float* cat = alloc((size_t)N * 192);
    // union region: knn partial lists vs MLP activations (disjoint in time)
    size_t zsz = (size_t)N * NSLICE * KNN;           // 5.24M
    size_t mlp = (size_t)N * (1024 + 256 + 128);     // 11.5M
    float* Z   = alloc(2 * zsz > mlp ? 2 * zsz : mlp);
    float* pd  = Z;
    int*   pi  = (int*)(Z + zsz);
    float* a1  = Z;
    float* a2  = a1 + (size_t)N * 1024;
    float* a3  = a2 + (size_t)N * 256;

    const int G = N / 64;  // 128 point groups

    // ---- stage 1 (C=3)
    rowsq_kernel<3><<<N / 256, 256, 0, stream>>>(x, sq, N);
    knn_part_kernel<3, 4><<<dim3(G, NSLICE / 4), 256, 0, stream>>>(x, sq, pd, pi, N);
    knn_merge_kernel<<<N / 8, 256, 0, stream>>>(pd, pi, nbr, N);
    prep_w_kernel<3><<<2, 256, 0, stream>>>(w1, b1, WW, bb);
    ec_gemm_kernel<3><<<N / 32, 128, 0, stream>>>(x, WW, bb, AB, N);
    ec_max_kernel<<<N / 4, 256, 0, stream>>>(AB, nbr, x1, N);
    // ---- stage 2 (C=64)
    rowsq_kernel<64><<<N / 256, 256, 0, stream>>>(x1, sq, N);
    knn_part_kernel<64, 3><<<dim3(G, NSLICE / 4), 256, 0, stream>>>(x1, sq, pd, pi, N);
    knn_merge_kernel<<<N / 8, 256, 0, stream>>>(pd, pi, nbr, N);
    prep_w_kernel<64><<<32, 256, 0, stream>>>(w2, b2, WW, bb);
    ec_gemm_kernel<64><<<N / 32, 128, 0, stream>>>(x1, WW, bb, AB, N);
    ec_max_kernel<<<N / 4, 256, 0, stream>>>(AB, nbr, x2, N);
    // ---- stage 3 (C=64)
    rowsq_kernel<64><<<N / 256, 256, 0, stream>>>(x2, sq, N);
    knn_part_kernel<64, 3><<<dim3(G, NSLICE / 4), 256, 0, stream>>>(x2, sq, pd, pi, N);
    knn_merge_kernel<<<N / 8, 256, 0, stream>>>(pd, pi, nbr, N);
    prep_w_kernel<64><<<32, 256, 0, stream>>>(w3, b3, WW, bb);
    ec_gemm_kernel<64><<<N / 32, 128, 0, stream>>>(x2, WW, bb, AB, N);
    ec_max_kernel<<<N / 4, 256, 0, stream>>>(AB, nbr, x3, N);
    // ---- MLP head
    concat3_kernel<<<(N * 192 + 255) / 256, 256, 0, stream>>>(x1, x2, x3, cat, N);
    gemm_bias_relu<true><<<dim3(1024 / 64, N / 64), 256, 0, stream>>>(cat, wl1, bl1, a1, N, 1024, 192);
    gemm_bias_relu<true><<<dim3(256 / 64, N / 64), 256, 0, stream>>>(a1, wm1, bm1, a2, N, 256, 1024);
    gemm_bias_relu<true><<<dim3(128 / 64, N / 64), 256, 0, stream>>>(a2, wm2, bm2, a3, N, 128, 256);
    last_layer_kernel<<<(N + 255) / 256, 256, 0, stream>>>(a3, wm3, bm3, out, N);
}

// Round 3
// 1245.395 us; speedup vs baseline: 4.5058x; 3.2648x over previous
//
#include <hip/hip_runtime.h>
#include <hip/hip_bf16.h>
#include <math.h>

#define KNN 20
#define CHSZ 2048   // candidate chunk size for distance matrix

// ---------------------------------------------------------------- rowsq
template<int C>
__global__ void rowsq_kernel(const float* __restrict__ x, float* __restrict__ sq, int N) {
    int i = blockIdx.x * blockDim.x + threadIdx.x;
    if (i >= N) return;
    float s = 0.f;
    if constexpr (C == 64) {
        const float4* p = reinterpret_cast<const float4*>(x + (size_t)i * C);
#pragma unroll
        for (int c = 0; c < 16; ++c) {
            float4 v = p[c];
            s += v.x * v.x + v.y * v.y + v.z * v.z + v.w * v.w;
        }
    } else {
#pragma unroll
        for (int c = 0; c < C; ++c) { float v = x[(size_t)i * C + c]; s += v * v; }
    }
    sq[i] = s;
}

// ---------------------------------------------------------------- dist GEMM (C=64)
// D[m][n] = sq[m] + sq[jb+n] - 2 * dot(X[m], X[jb+n]);  diagonal -> +inf.
// 128x128 tile, BK=8, 256 threads, 8x8 per thread. Small state, no spills.
__global__ __launch_bounds__(256, 2) void dist_gemm_kernel(
    const float* __restrict__ X, const float* __restrict__ sq,
    float* __restrict__ D, int N, int chunk_base) {
    constexpr int K = 64, BK = 8, ST = 132;  // padded LDS stride (16B-aligned rows)
    __shared__ float As[BK * ST];
    __shared__ float Bs[BK * ST];
    const int tid = threadIdx.x;
    const int tx = tid & 15, ty = tid >> 4;
    const int m0 = blockIdx.y * 128;
    const int n0 = blockIdx.x * 128;          // chunk-local
    const int jb = chunk_base + n0;           // global candidate base
    const int sr = tid >> 1, skq = tid & 1;   // staging: row 0..127, k-quad 0..1

    float acc[8][8] = {};

    for (int k0 = 0; k0 < K; k0 += BK) {
        float4 va = *reinterpret_cast<const float4*>(X + (size_t)(m0 + sr) * K + k0 + 4 * skq);
        float4 vb = *reinterpret_cast<const float4*>(X + (size_t)(jb + sr) * K + k0 + 4 * skq);
        As[(4 * skq + 0) * ST + sr] = va.x;
        As[(4 * skq + 1) * ST + sr] = va.y;
        As[(4 * skq + 2) * ST + sr] = va.z;
        As[(4 * skq + 3) * ST + sr] = va.w;
        Bs[(4 * skq + 0) * ST + sr] = vb.x;
        Bs[(4 * skq + 1) * ST + sr] = vb.y;
        Bs[(4 * skq + 2) * ST + sr] = vb.z;
        Bs[(4 * skq + 3) * ST + sr] = vb.w;
        __syncthreads();
#pragma unroll
        for (int kk = 0; kk < BK; ++kk) {
            float4 alo = *reinterpret_cast<const float4*>(&As[kk * ST + ty * 4]);
            float4 ahi = *reinterpret_cast<const float4*>(&As[kk * ST + 64 + ty * 4]);
            float4 blo = *reinterpret_cast<const float4*>(&Bs[kk * ST + tx * 4]);
            float4 bhi = *reinterpret_cast<const float4*>(&Bs[kk * ST + 64 + tx * 4]);
            float a[8] = {alo.x, alo.y, alo.z, alo.w, ahi.x, ahi.y, ahi.z, ahi.w};
            float b[8] = {blo.x, blo.y, blo.z, blo.w, bhi.x, bhi.y, bhi.z, bhi.w};
#pragma unroll
            for (int u = 0; u < 8; ++u)
#pragma unroll
                for (int v = 0; v < 8; ++v) acc[u][v] += a[u] * b[v];
        }
        __syncthreads();
    }

    int mm[8], jn[8];
    float sm[8], sn[8];
#pragma unroll
    for (int u = 0; u < 8; ++u) {
        mm[u] = m0 + (u < 4 ? ty * 4 + u : 64 + ty * 4 + (u - 4));
        sm[u] = sq[mm[u]];
    }
#pragma unroll
    for (int v = 0; v < 8; ++v) {
        int nn = (v < 4 ? tx * 4 + v : 64 + tx * 4 + (v - 4));
        jn[v] = jb + nn;
        sn[v] = sq[jn[v]];
    }
#pragma unroll
    for (int u = 0; u < 8; ++u) {
        float4 lo, hi;
        float* lp = &lo.x; float* hp = &hi.x;
#pragma unroll
        for (int v = 0; v < 4; ++v) {
            float val = sm[u] + sn[v] - 2.f * acc[u][v];
            if (mm[u] == jn[v]) val = INFINITY;
            lp[v] = val;
        }
#pragma unroll
        for (int v = 4; v < 8; ++v) {
            float val = sm[u] + sn[v] - 2.f * acc[u][v];
            if (mm[u] == jn[v]) val = INFINITY;
            hp[v - 4] = val;
        }
        *reinterpret_cast<float4*>(D + (size_t)mm[u] * CHSZ + n0 + tx * 4) = lo;
        *reinterpret_cast<float4*>(D + (size_t)mm[u] * CHSZ + n0 + 64 + tx * 4) = hi;
    }
}

// ---------------------------------------------------------------- dist (C=3)
// Thread computes one float4 of D. Memory-bound on the D write.
__global__ __launch_bounds__(256) void dist3_kernel(
    const float* __restrict__ X, const float* __restrict__ sq,
    float* __restrict__ D, int N, int chunk_base) {
    const int t = blockIdx.x * 256 + threadIdx.x;
    const int per_row = CHSZ / 4;
    const int p = t / per_row, q = t - p * per_row;
    const int j0 = chunk_base + q * 4;
    const float x0 = X[(size_t)p * 3], x1 = X[(size_t)p * 3 + 1], x2 = X[(size_t)p * 3 + 2];
    const float sp = sq[p];
    const float* xr = X + (size_t)j0 * 3;
    float v[4];
#pragma unroll
    for (int k = 0; k < 4; ++k) {
        float dot = x0 * xr[k * 3 + 0] + x1 * xr[k * 3 + 1] + x2 * xr[k * 3 + 2];
        float d = sp + sq[j0 + k] - 2.f * dot;
        v[k] = (j0 + k == p) ? INFINITY : d;
    }
    float4 o = {v[0], v[1], v[2], v[3]};
    *reinterpret_cast<float4*>(D + (size_t)p * CHSZ + q * 4) = o;
}

// ---------------------------------------------------------------- knn select
// One wave per point. Running top-20 distributed one entry per lane (lanes
// 0..19), sorted ascending by lex (dist, idx) == jax.lax.top_k tie-break.
// Fast path: float4 load + compare vs current 20th + ballot (usually 0).
// Insertion: ballot-rank + shfl_up shift, branchless, ~20 instr.
__global__ __launch_bounds__(256) void knn_select_kernel(
    const float* __restrict__ D, float* __restrict__ sd, int* __restrict__ si,
    int* __restrict__ nbrs, int chunk_base, int first, int last) {
    const int tid = threadIdx.x;
    const int w = tid >> 6, l = tid & 63;
    const int p = blockIdx.x * 4 + w;

    float dl = INFINITY; int il = 0x7fffffff;
    if (!first && l < KNN) { dl = sd[(size_t)p * KNN + l]; il = si[(size_t)p * KNN + l]; }
    float td = __shfl(dl, 19); int ti = __shfl(il, 19);

    const float4* Drow = reinterpret_cast<const float4*>(D + (size_t)p * CHSZ);
#pragma unroll 1
    for (int b = 0; b < CHSZ / 256; ++b) {
        float4 v = Drow[b * 64 + l];
        // coarse filter: <= threshold (ties resolved exactly in slow path)
        bool q0 = v.x <= td, q1 = v.y <= td, q2 = v.z <= td, q3 = v.w <= td;
        unsigned long long anyb = __ballot(q0 | q1 | q2 | q3);
        if (!anyb) continue;
#pragma unroll
        for (int qq = 0; qq < 4; ++qq) {
            float vq = (qq == 0) ? v.x : (qq == 1) ? v.y : (qq == 2) ? v.z : v.w;
            unsigned long long bal = __ballot((qq == 0) ? q0 : (qq == 1) ? q1 : (qq == 2) ? q2 : q3);
            while (bal) {
                int ln = __ffsll((unsigned long long)bal) - 1;
                bal &= bal - 1;
                float cv = __shfl(vq, ln);
                int cj = chunk_base + b * 256 + 4 * ln + qq;
                // exact lex re-check against the CURRENT 20th entry
                if (cv < td || (cv == td && cj < ti)) {
                    bool cmp = (dl < cv) || (dl == cv && il < cj);
                    unsigned long long cb = __ballot(cmp) & 0xFFFFFull;
                    int r = __popcll(cb);
                    float sdl = __shfl_up(dl, 1);
                    int sil = __shfl_up(il, 1);
                    if (l == r) { dl = cv; il = cj; }
                    else if (l > r && l < KNN) { dl = sdl; il = sil; }
                    td = __shfl(dl, 19); ti = __shfl(il, 19);
                }
            }
        }
    }
    if (l < KNN) {
        sd[(size_t)p * KNN + l] = dl;
        si[(size_t)p * KNN + l] = il;
        if (last) nbrs[(size_t)p * KNN + l] = il;
    }
}

// ---------------------------------------------------------------- edgeconv (factored)
// e_ij = (W1-W2)^T xi + b  +  W2^T xj ; out = max_j relu(.)
template<int C>
__global__ void prep_w_kernel(const float* __restrict__ w, const float* __restrict__ b,
                              float* __restrict__ WW, float* __restrict__ bb) {
    int t = blockIdx.x * blockDim.x + threadIdx.x;
    if (t < 128) bb[t] = (t < 64) ? b[t] : 0.f;
    if (t >= C * 128) return;
    int c = t >> 7, f = t & 127;
    WW[t] = (f < 64) ? (w[c * 64 + f] - w[(C + c) * 64 + f]) : w[(C + c) * 64 + (f - 64)];
}

template<int C>
__global__ __launch_bounds__(128) void ec_gemm_kernel(
    const float* __restrict__ x, const float* __restrict__ WW,
    const float* __restrict__ bb, float* __restrict__ AB, int N) {
    __shared__ float Ws[C * 128];
    __shared__ float xs[32 * C];
    const int tid = threadIdx.x;
    const int r0 = blockIdx.x * 32;
    for (int idx = tid; idx < C * 128; idx += 128) Ws[idx] = WW[idx];
    for (int idx = tid; idx < 32 * C; idx += 128) xs[idx] = x[(size_t)r0 * C + idx];
    __syncthreads();
    const float bias = bb[tid];
#pragma unroll 1
    for (int r = 0; r < 32; ++r) {
        float acc = bias;
#pragma unroll
        for (int c = 0; c < C; ++c) acc = fmaf(xs[r * C + c], Ws[c * 128 + tid], acc);
        AB[(size_t)(r0 + r) * 128 + tid] = acc;
    }
}

__global__ __launch_bounds__(256) void ec_max_kernel(
    const float* __restrict__ AB, const int* __restrict__ nbrs,
    float* __restrict__ out, int N) {
    const int tid = threadIdx.x;
    const int w = tid >> 6, f = tid & 63;
    const int i = blockIdx.x * 4 + w;
    const float a = AB[(size_t)i * 128 + f];
    const int* nb = nbrs + (size_t)i * KNN;
    float m = -3.4e38f;
#pragma unroll
    for (int j = 0; j < KNN; ++j) {
        int n = nb[j];
        m = fmaxf(m, AB[(size_t)n * 128 + 64 + f]);
    }
    out[(size_t)i * 64 + f] = fmaxf(a + m, 0.f);
}

// ---------------------------------------------------------------- concat
__global__ void concat3_kernel(const float* __restrict__ a, const float* __restrict__ b,
                               const float* __restrict__ c, float* __restrict__ o, int N) {
    int t = blockIdx.x * blockDim.x + threadIdx.x;
    if (t >= N * 192) return;
    int r = t / 192, cc = t % 192;
    float v;
    if (cc < 64) v = a[(size_t)r * 64 + cc];
    else if (cc < 128) v = b[(size_t)r * 64 + cc - 64];
    else v = c[(size_t)r * 64 + cc - 128];
    o[t] = v;
}

// ---------------------------------------------------------------- GEMM (MLP head)
template<bool RELU>
__global__ __launch_bounds__(256) void gemm_bias_relu(
    const float* __restrict__ A, const float* __restrict__ B,
    const float* __restrict__ bias, float* __restrict__ C,
    int M, int N, int K) {
    constexpr int BM = 64, BN = 64, BK = 16;
    __shared__ float As[BK][BM + 1];
    __shared__ float Bs[BK][BN + 1];
    const int tid = threadIdx.x;
    const int tx = tid & 15, ty = tid >> 4;
    const int m0 = blockIdx.y * BM, n0 = blockIdx.x * BN;
    float acc[4][4] = {};

    for (int k0 = 0; k0 < K; k0 += BK) {
        for (int idx = tid; idx < BM * BK; idx += 256) {
            int r = idx >> 4, c = idx & 15;
            As[c][r] = A[(size_t)(m0 + r) * K + k0 + c];
        }
        for (int idx = tid; idx < BK * BN; idx += 256) {
            int r = idx >> 6, c = idx & 63;
            Bs[r][c] = B[(size_t)(k0 + r) * N + n0 + c];
        }
        __syncthreads();
#pragma unroll
        for (int kk = 0; kk < BK; ++kk) {
            float a[4], b[4];
#pragma unroll
            for (int u = 0; u < 4; ++u) a[u] = As[kk][ty + 16 * u];
#pragma unroll
            for (int v = 0; v < 4; ++v) b[v] = Bs[kk][tx + 16 * v];
#pragma unroll
            for (int u = 0; u < 4; ++u)
#pragma unroll
                for (int v = 0; v < 4; ++v) acc[u][v] += a[u] * b[v];
        }
        __syncthreads();
    }
#pragma unroll
    for (int u = 0; u < 4; ++u) {
        int m = m0 + ty + 16 * u;
#pragma unroll
        for (int v = 0; v < 4; ++v) {
            int n = n0 + tx + 16 * v;
            float val = acc[u][v] + bias[n];
            if (RELU) val = fmaxf(val, 0.f);
            C[(size_t)m * N + n] = val;
        }
    }
}

// ---------------------------------------------------------------- last layer + log_softmax
__global__ __launch_bounds__(256) void last_layer_kernel(
    const float* __restrict__ A, const float* __restrict__ W,
    const float* __restrict__ b, float* __restrict__ out, int N) {
    constexpr int KD = 128, NC = 13;
    __shared__ float ws[KD * NC];
    __shared__ float bs[NC];
    const int tid = threadIdx.x;
    for (int idx = tid; idx < KD * NC; idx += 256) ws[idx] = W[idx];
    if (tid < NC) bs[tid] = b[tid];
    __syncthreads();
    int r = blockIdx.x * 256 + tid;
    if (r >= N) return;
    float acc[NC];
#pragma unroll
    for (int f = 0; f < NC; ++f) acc[f] = bs[f];
    const float4* row = reinterpret_cast<const float4*>(A + (size_t)r * KD);
#pragma unroll 4
    for (int c4 = 0; c4 < KD / 4; ++c4) {
        float4 v = row[c4];
#pragma unroll
        for (int f = 0; f < NC; ++f) acc[f] += v.x * ws[(c4 * 4 + 0) * NC + f];
#pragma unroll
        for (int f = 0; f < NC; ++f) acc[f] += v.y * ws[(c4 * 4 + 1) * NC + f];
#pragma unroll
        for (int f = 0; f < NC; ++f) acc[f] += v.z * ws[(c4 * 4 + 2) * NC + f];
#pragma unroll
        for (int f = 0; f < NC; ++f) acc[f] += v.w * ws[(c4 * 4 + 3) * NC + f];
    }
    float m = acc[0];
#pragma unroll
    for (int f = 1; f < NC; ++f) m = fmaxf(m, acc[f]);
    float s = 0.f;
#pragma unroll
    for (int f = 0; f < NC; ++f) s += expf(acc[f] - m);
    float ls = logf(s);
#pragma unroll
    for (int f = 0; f < NC; ++f) out[(size_t)r * NC + f] = acc[f] - m - ls;
}

// ---------------------------------------------------------------- launch
extern "C" void kernel_launch(void* const* d_in, const int* in_sizes, int n_in,
                              void* d_out, int out_size, void* d_ws, size_t ws_size,
                              hipStream_t stream) {
    const float* x   = (const float*)d_in[0];
    const float* w1  = (const float*)d_in[1];
    const float* b1  = (const float*)d_in[2];
    const float* w2  = (const float*)d_in[3];
    const float* b2  = (const float*)d_in[4];
    const float* w3  = (const float*)d_in[5];
    const float* b3  = (const float*)d_in[6];
    const float* wl1 = (const float*)d_in[7];
    const float* bl1 = (const float*)d_in[8];
    const float* wm1 = (const float*)d_in[9];
    const float* bm1 = (const float*)d_in[10];
    const float* wm2 = (const float*)d_in[11];
    const float* bm2 = (const float*)d_in[12];
    const float* wm3 = (const float*)d_in[13];
    const float* bm3 = (const float*)d_in[14];
    float* out = (float*)d_out;

    const int N = in_sizes[0] / 3;  // 8192
    const int NCH = N / CHSZ;       // 4 chunks

    float* ws = (float*)d_ws;
    size_t off = 0;
    auto alloc = [&](size_t n) { float* p = ws + off; off += n; return p; };
    float* sq  = alloc(N);
    int*   nbr = (int*)alloc((size_t)N * KNN);
    float* x1  = alloc((size_t)N * 64);
    float* x2  = alloc((size_t)N * 64);
    float* x3  = alloc((size_t)N * 64);
    float* AB  = alloc((size_t)N * 128);
    float* WW  = alloc(64 * 128);
    float* bb  = alloc(128);
    float* cat = alloc((size_t)N * 192);
    float* sd  = alloc((size_t)N * KNN);
    int*   si  = (int*)alloc((size_t)N * KNN);
    // union: D chunk (knn phase) vs MLP activations (head phase)
    size_t dsz = (size_t)N * CHSZ;                   // 16.8M
    size_t mlp = (size_t)N * (1024 + 256 + 128);     // 11.5M
    float* Z   = alloc(dsz > mlp ? dsz : mlp);
    float* D   = Z;
    float* a1  = Z;
    float* a2  = a1 + (size_t)N * 1024;
    float* a3  = a2 + (size_t)N * 256;

    // ---- stage 1 (C=3)
    rowsq_kernel<3><<<N / 256, 256, 0, stream>>>(x, sq, N);
    for (int c = 0; c < NCH; ++c) {
        dist3_kernel<<<(size_t)N * CHSZ / 4 / 256, 256, 0, stream>>>(x, sq, D, N, c * CHSZ);
        knn_select_kernel<<<N / 4, 256, 0, stream>>>(D, sd, si, nbr, c * CHSZ, c == 0, c == NCH - 1);
    }
    prep_w_kernel<3><<<2, 256, 0, stream>>>(w1, b1, WW, bb);
    ec_gemm_kernel<3><<<N / 32, 128, 0, stream>>>(x, WW, bb, AB, N);
    ec_max_kernel<<<N / 4, 256, 0, stream>>>(AB, nbr, x1, N);
    // ---- stage 2 (C=64)
    rowsq_kernel<64><<<N / 256, 256, 0, stream>>>(x1, sq, N);
    for (int c = 0; c < NCH; ++c) {
        dist_gemm_kernel<<<dim3(CHSZ / 128, N / 128), 256, 0, stream>>>(x1, sq, D, N, c * CHSZ);
        knn_select_kernel<<<N / 4, 256, 0, stream>>>(D, sd, si, nbr, c * CHSZ, c == 0, c == NCH - 1);
    }
    prep_w_kernel<64><<<32, 256, 0, stream>>>(w2, b2, WW, bb);
    ec_gemm_kernel<64><<<N / 32, 128, 0, stream>>>(x1, WW, bb, AB, N);
    ec_max_kernel<<<N / 4, 256, 0, stream>>>(AB, nbr, x2, N);
    // ---- stage 3 (C=64)
    rowsq_kernel<64><<<N / 256, 256, 0, stream>>>(x2, sq, N);
    for (int c = 0; c < NCH; ++c) {
        dist_gemm_kernel<<<dim3(CHSZ / 128, N / 128), 256, 0, stream>>>(x2, sq, D, N, c * CHSZ);
        knn_select_kernel<<<N / 4, 256, 0, stream>>>(D, sd, si, nbr, c * CHSZ, c == 0, c == NCH - 1);
    }
    prep_w_kernel<64><<<32, 256, 0, stream>>>(w3, b3, WW, bb);
    ec_gemm_kernel<64><<<N / 32, 128, 0, stream>>>(x2, WW, bb, AB, N);
    ec_max_kernel<<<N / 4, 256, 0, stream>>>(AB, nbr, x3, N);
    // ---- MLP head
    concat3_kernel<<<(N * 192 + 255) / 256, 256, 0, stream>>>(x1, x2, x3, cat, N);
    gemm_bias_relu<true><<<dim3(1024 / 64, N / 64), 256, 0, stream>>>(cat, wl1, bl1, a1, N, 1024, 192);
    gemm_bias_relu<true><<<dim3(256 / 64, N / 64), 256, 0, stream>>>(a1, wm1, bm1, a2, N, 256, 1024);
    gemm_bias_relu<true><<<dim3(128 / 64, N / 64), 256, 0, stream>>>(a2, wm2, bm2, a3, N, 128, 256);
    last_layer_kernel<<<(N + 255) / 256, 256, 0, stream>>>(a3, wm3, bm3, out, N);
}

// Round 4
// 1062.021 us; speedup vs baseline: 5.2837x; 1.1727x over previous
//
#include <hip/hip_runtime.h>
#include <hip/hip_bf16.h>
#include <math.h>

#define KNN 20
#define CHSZ 2048   // candidate chunk size for distance matrix

typedef __attribute__((ext_vector_type(8))) short bf16x8_t;
typedef __attribute__((ext_vector_type(4))) float f32x4_t;

// bf16 split helpers (RNE)
__device__ __forceinline__ unsigned short f2bf(float f) {
    unsigned u = __float_as_uint(f);
    u += 0x7fffu + ((u >> 16) & 1u);
    return (unsigned short)(u >> 16);
}
__device__ __forceinline__ float bf2f(unsigned short h) {
    return __uint_as_float((unsigned)h << 16);
}

// async global->LDS, 16 B per lane; dest = wave-uniform base + lane*16
__device__ __forceinline__ void gload_lds16(const void* g, void* l) {
    auto gp = reinterpret_cast<const __attribute__((address_space(1))) unsigned*>(
        reinterpret_cast<uintptr_t>(g));
    auto lp = reinterpret_cast<__attribute__((address_space(3))) unsigned*>(
        reinterpret_cast<uintptr_t>(l));
    __builtin_amdgcn_global_load_lds(gp, lp, 16, 0, 0);
}

// ---------------------------------------------------------------- rowsq
template<int C>
__global__ void rowsq_kernel(const float* __restrict__ x, float* __restrict__ sq, int N) {
    int i = blockIdx.x * blockDim.x + threadIdx.x;
    if (i >= N) return;
    float s = 0.f;
    if constexpr (C == 64) {
        const float4* p = reinterpret_cast<const float4*>(x + (size_t)i * C);
#pragma unroll
        for (int c = 0; c < 16; ++c) {
            float4 v = p[c];
            s += v.x * v.x + v.y * v.y + v.z * v.z + v.w * v.w;
        }
    } else {
#pragma unroll
        for (int c = 0; c < C; ++c) { float v = x[(size_t)i * C + c]; s += v * v; }
    }
    sq[i] = s;
}

// ---------------------------------------------------------------- dist GEMM (C=64, fp32 exact)
__global__ __launch_bounds__(256, 2) void dist_gemm_kernel(
    const float* __restrict__ X, const float* __restrict__ sq,
    float* __restrict__ D, int N, int chunk_base) {
    constexpr int K = 64, BK = 8, ST = 132;
    __shared__ float As[BK * ST];
    __shared__ float Bs[BK * ST];
    const int tid = threadIdx.x;
    const int tx = tid & 15, ty = tid >> 4;
    const int m0 = blockIdx.y * 128;
    const int n0 = blockIdx.x * 128;
    const int jb = chunk_base + n0;
    const int sr = tid >> 1, skq = tid & 1;

    float acc[8][8] = {};

    for (int k0 = 0; k0 < K; k0 += BK) {
        float4 va = *reinterpret_cast<const float4*>(X + (size_t)(m0 + sr) * K + k0 + 4 * skq);
        float4 vb = *reinterpret_cast<const float4*>(X + (size_t)(jb + sr) * K + k0 + 4 * skq);
        As[(4 * skq + 0) * ST + sr] = va.x;
        As[(4 * skq + 1) * ST + sr] = va.y;
        As[(4 * skq + 2) * ST + sr] = va.z;
        As[(4 * skq + 3) * ST + sr] = va.w;
        Bs[(4 * skq + 0) * ST + sr] = vb.x;
        Bs[(4 * skq + 1) * ST + sr] = vb.y;
        Bs[(4 * skq + 2) * ST + sr] = vb.z;
        Bs[(4 * skq + 3) * ST + sr] = vb.w;
        __syncthreads();
#pragma unroll
        for (int kk = 0; kk < BK; ++kk) {
            float4 alo = *reinterpret_cast<const float4*>(&As[kk * ST + ty * 4]);
            float4 ahi = *reinterpret_cast<const float4*>(&As[kk * ST + 64 + ty * 4]);
            float4 blo = *reinterpret_cast<const float4*>(&Bs[kk * ST + tx * 4]);
            float4 bhi = *reinterpret_cast<const float4*>(&Bs[kk * ST + 64 + tx * 4]);
            float a[8] = {alo.x, alo.y, alo.z, alo.w, ahi.x, ahi.y, ahi.z, ahi.w};
            float b[8] = {blo.x, blo.y, blo.z, blo.w, bhi.x, bhi.y, bhi.z, bhi.w};
#pragma unroll
            for (int u = 0; u < 8; ++u)
#pragma unroll
                for (int v = 0; v < 8; ++v) acc[u][v] += a[u] * b[v];
        }
        __syncthreads();
    }

    int mm[8], jn[8];
    float sm[8], sn[8];
#pragma unroll
    for (int u = 0; u < 8; ++u) {
        mm[u] = m0 + (u < 4 ? ty * 4 + u : 64 + ty * 4 + (u - 4));
        sm[u] = sq[mm[u]];
    }
#pragma unroll
    for (int v = 0; v < 8; ++v) {
        int nn = (v < 4 ? tx * 4 + v : 64 + tx * 4 + (v - 4));
        jn[v] = jb + nn;
        sn[v] = sq[jn[v]];
    }
#pragma unroll
    for (int u = 0; u < 8; ++u) {
        float4 lo, hi;
        float* lp = &lo.x; float* hp = &hi.x;
#pragma unroll
        for (int v = 0; v < 4; ++v) {
            float val = sm[u] + sn[v] - 2.f * acc[u][v];
            if (mm[u] == jn[v]) val = INFINITY;
            lp[v] = val;
        }
#pragma unroll
        for (int v = 4; v < 8; ++v) {
            float val = sm[u] + sn[v] - 2.f * acc[u][v];
            if (mm[u] == jn[v]) val = INFINITY;
            hp[v - 4] = val;
        }
        *reinterpret_cast<float4*>(D + (size_t)mm[u] * CHSZ + n0 + tx * 4) = lo;
        *reinterpret_cast<float4*>(D + (size_t)mm[u] * CHSZ + n0 + 64 + tx * 4) = hi;
    }
}

// ---------------------------------------------------------------- dist (C=3)
__global__ __launch_bounds__(256) void dist3_kernel(
    const float* __restrict__ X, const float* __restrict__ sq,
    float* __restrict__ D, int N, int chunk_base) {
    const int t = blockIdx.x * 256 + threadIdx.x;
    const int per_row = CHSZ / 4;
    const int p = t / per_row, q = t - p * per_row;
    const int j0 = chunk_base + q * 4;
    const float x0 = X[(size_t)p * 3], x1 = X[(size_t)p * 3 + 1], x2 = X[(size_t)p * 3 + 2];
    const float sp = sq[p];
    const float* xr = X + (size_t)j0 * 3;
    float v[4];
#pragma unroll
    for (int k = 0; k < 4; ++k) {
        float dot = x0 * xr[k * 3 + 0] + x1 * xr[k * 3 + 1] + x2 * xr[k * 3 + 2];
        float d = sp + sq[j0 + k] - 2.f * dot;
        v[k] = (j0 + k == p) ? INFINITY : d;
    }
    float4 o = {v[0], v[1], v[2], v[3]};
    *reinterpret_cast<float4*>(D + (size_t)p * CHSZ + q * 4) = o;
}

// ---------------------------------------------------------------- knn select
__global__ __launch_bounds__(256) void knn_select_kernel(
    const float* __restrict__ D, float* __restrict__ sd, int* __restrict__ si,
    int* __restrict__ nbrs, int chunk_base, int first, int last) {
    const int tid = threadIdx.x;
    const int w = tid >> 6, l = tid & 63;
    const int p = blockIdx.x * 4 + w;

    float dl = INFINITY; int il = 0x7fffffff;
    if (!first && l < KNN) { dl = sd[(size_t)p * KNN + l]; il = si[(size_t)p * KNN + l]; }
    float td = __shfl(dl, 19); int ti = __shfl(il, 19);

    const float4* Drow = reinterpret_cast<const float4*>(D + (size_t)p * CHSZ);
#pragma unroll 1
    for (int b = 0; b < CHSZ / 256; ++b) {
        float4 v = Drow[b * 64 + l];
        bool q0 = v.x <= td, q1 = v.y <= td, q2 = v.z <= td, q3 = v.w <= td;
        unsigned long long anyb = __ballot(q0 | q1 | q2 | q3);
        if (!anyb) continue;
#pragma unroll
        for (int qq = 0; qq < 4; ++qq) {
            float vq = (qq == 0) ? v.x : (qq == 1) ? v.y : (qq == 2) ? v.z : v.w;
            unsigned long long bal = __ballot((qq == 0) ? q0 : (qq == 1) ? q1 : (qq == 2) ? q2 : q3);
            while (bal) {
                int ln = __ffsll((unsigned long long)bal) - 1;
                bal &= bal - 1;
                float cv = __shfl(vq, ln);
                int cj = chunk_base + b * 256 + 4 * ln + qq;
                if (cv < td || (cv == td && cj < ti)) {
                    bool cmp = (dl < cv) || (dl == cv && il < cj);
                    unsigned long long cb = __ballot(cmp) & 0xFFFFFull;
                    int r = __popcll(cb);
                    float sdl = __shfl_up(dl, 1);
                    int sil = __shfl_up(il, 1);
                    if (l == r) { dl = cv; il = cj; }
                    else if (l > r && l < KNN) { dl = sdl; il = sil; }
                    td = __shfl(dl, 19); ti = __shfl(il, 19);
                }
            }
        }
    }
    if (l < KNN) {
        sd[(size_t)p * KNN + l] = dl;
        si[(size_t)p * KNN + l] = il;
        if (last) nbrs[(size_t)p * KNN + l] = il;
    }
}

// ---------------------------------------------------------------- edgeconv (factored, fp32 exact)
template<int C>
__global__ void prep_w_kernel(const float* __restrict__ w, const float* __restrict__ b,
                              float* __restrict__ WW, float* __restrict__ bb) {
    int t = blockIdx.x * blockDim.x + threadIdx.x;
    if (t < 128) bb[t] = (t < 64) ? b[t] : 0.f;
    if (t >= C * 128) return;
    int c = t >> 7, f = t & 127;
    WW[t] = (f < 64) ? (w[c * 64 + f] - w[(C + c) * 64 + f]) : w[(C + c) * 64 + (f - 64)];
}

template<int C>
__global__ __launch_bounds__(128) void ec_gemm_kernel(
    const float* __restrict__ x, const float* __restrict__ WW,
    const float* __restrict__ bb, float* __restrict__ AB, int N) {
    __shared__ float Ws[C * 128];
    __shared__ float xs[32 * C];
    const int tid = threadIdx.x;
    const int r0 = blockIdx.x * 32;
    for (int idx = tid; idx < C * 128; idx += 128) Ws[idx] = WW[idx];
    for (int idx = tid; idx < 32 * C; idx += 128) xs[idx] = x[(size_t)r0 * C + idx];
    __syncthreads();
    const float bias = bb[tid];
#pragma unroll 1
    for (int r = 0; r < 32; ++r) {
        float acc = bias;
#pragma unroll
        for (int c = 0; c < C; ++c) acc = fmaf(xs[r * C + c], Ws[c * 128 + tid], acc);
        AB[(size_t)(r0 + r) * 128 + tid] = acc;
    }
}

__global__ __launch_bounds__(256) void ec_max_kernel(
    const float* __restrict__ AB, const int* __restrict__ nbrs,
    float* __restrict__ out, int N) {
    const int tid = threadIdx.x;
    const int w = tid >> 6, f = tid & 63;
    const int i = blockIdx.x * 4 + w;
    const float a = AB[(size_t)i * 128 + f];
    const int* nb = nbrs + (size_t)i * KNN;
    float m = -3.4e38f;
#pragma unroll
    for (int j = 0; j < KNN; ++j) {
        int n = nb[j];
        m = fmaxf(m, AB[(size_t)n * 128 + 64 + f]);
    }
    out[(size_t)i * 64 + f] = fmaxf(a + m, 0.f);
}

// ---------------------------------------------------------------- concat + split to bf16 hi/lo
__global__ void concat_split_kernel(const float* __restrict__ a, const float* __restrict__ b,
                                    const float* __restrict__ c,
                                    unsigned short* __restrict__ hi, unsigned short* __restrict__ lo,
                                    int N) {
    int t = blockIdx.x * blockDim.x + threadIdx.x;
    if (t >= N * 192) return;
    int r = t / 192, cc = t % 192;
    float v;
    if (cc < 64) v = a[(size_t)r * 64 + cc];
    else if (cc < 128) v = b[(size_t)r * 64 + cc - 64];
    else v = c[(size_t)r * 64 + cc - 128];
    unsigned short h = f2bf(v);
    hi[t] = h;
    lo[t] = f2bf(v - bf2f(h));
}

// ---------------------------------------------------------------- weight split: BT[F][3K]
// k' in [0,K): hi(W[k'][n]); [K,2K): lo(W[k'-K][n]); [2K,3K): hi(W[k'-2K][n])
__global__ void prep_bsplit_kernel(const float* __restrict__ W, unsigned short* __restrict__ BT,
                                   int K, int F) {
    int t = blockIdx.x * 256 + threadIdx.x;
    int K3 = 3 * K;
    if (t >= F * K3) return;
    int n = t / K3, kp = t - n * K3;
    int seg = kp / K;
    int k = kp - seg * K;
    float v = W[(size_t)k * F + n];
    unsigned short h = f2bf(v);
    BT[t] = (seg == 1) ? f2bf(v - bf2f(h)) : h;
}

// ---------------------------------------------------------------- split-bf16 MFMA GEMM
// C[M,N] = relu(A[M,K] @ B[K,N] + bias) via A'=[Ah|Ah|Al], B'=[Bh;Bl;Bh] (K'=3K).
// A as two bf16 buffers (row-major [M][K]); B pre-transposed+split: BT [N][3K].
// Tiles: BM x BN, 4 waves (WR x WC of 64x64), 16x16x32 bf16 MFMA, BK=64.
// LDS staged via global_load_lds w=16 with XOR-octet swizzle (conflict-free b128 reads).
template<int BM, int BN, int SPLIT>
__global__ __launch_bounds__(256) void mfma_gemm_kernel(
    const unsigned short* __restrict__ Ahi, const unsigned short* __restrict__ Alo,
    const unsigned short* __restrict__ BT, const float* __restrict__ bias,
    float* __restrict__ Cf, unsigned short* __restrict__ Chi, unsigned short* __restrict__ Clo,
    int M, int N, int K) {
    constexpr int WR = BM / 64, WC = BN / 64;
    static_assert(WR * WC == 4, "4 waves");
    __shared__ __align__(16) unsigned short As[BM * 64];
    __shared__ __align__(16) unsigned short Bs[BN * 64];
    const int tid = threadIdx.x;
    const int w = tid >> 6, l = tid & 63;
    const int wr = w % WR, wc = w / WR;
    const int m0 = blockIdx.y * BM, n0 = blockIdx.x * BN;
    const int K3 = 3 * K;

    f32x4_t acc[4][4];
#pragma unroll
    for (int a = 0; a < 4; ++a)
#pragma unroll
        for (int b = 0; b < 4; ++b) acc[a][b] = (f32x4_t){0.f, 0.f, 0.f, 0.f};

    const int lr = l >> 3;                     // staging row-in-group 0..7
    const int swz = ((l & 7) ^ lr) * 8;        // swizzled octet fetch (elements)
    const int frow = l & 15;                   // fragment row
    const int fq = l >> 4;                     // fragment k-quad 0..3
    const int fswz = l & 7;                    // reader swizzle key

    for (int kt = 0; kt < K3 / 64; ++kt) {
        const int kk = kt * 64;
        const unsigned short* srcA; int k0;
        if (kk < K)            { srcA = Ahi; k0 = kk; }
        else if (kk < 2 * K)   { srcA = Ahi; k0 = kk - K; }
        else                   { srcA = Alo; k0 = kk - 2 * K; }
#pragma unroll
        for (int t = 0; t < BM / 32; ++t) {
            int row = w * (BM / 4) + t * 8;
            gload_lds16(srcA + (size_t)(m0 + row + lr) * K + k0 + swz,
                        (void*)(As + row * 64));
        }
#pragma unroll
        for (int t = 0; t < BN / 32; ++t) {
            int row = w * (BN / 4) + t * 8;
            gload_lds16(BT + (size_t)(n0 + row + lr) * K3 + kk + swz,
                        (void*)(Bs + row * 64));
        }
        __syncthreads();
#pragma unroll
        for (int ks = 0; ks < 2; ++ks) {
            bf16x8_t af[4], bf[4];
            const int o = (ks * 4 + fq) ^ fswz;
#pragma unroll
            for (int tm = 0; tm < 4; ++tm) {
                int row = wr * 64 + tm * 16 + frow;
                af[tm] = *reinterpret_cast<const bf16x8_t*>(As + row * 64 + o * 8);
            }
#pragma unroll
            for (int tn = 0; tn < 4; ++tn) {
                int row = wc * 64 + tn * 16 + frow;
                bf[tn] = *reinterpret_cast<const bf16x8_t*>(Bs + row * 64 + o * 8);
            }
#pragma unroll
            for (int tm = 0; tm < 4; ++tm)
#pragma unroll
                for (int tn = 0; tn < 4; ++tn)
                    acc[tm][tn] = __builtin_amdgcn_mfma_f32_16x16x32_bf16(
                        af[tm], bf[tn], acc[tm][tn], 0, 0, 0);
        }
        __syncthreads();
    }

    // epilogue: D layout col=lane&15, row=(lane>>4)*4+reg
#pragma unroll
    for (int tn = 0; tn < 4; ++tn) {
        int col = n0 + wc * 64 + tn * 16 + (l & 15);
        float bv = bias[col];
#pragma unroll
        for (int tm = 0; tm < 4; ++tm) {
#pragma unroll
            for (int r = 0; r < 4; ++r) {
                int row = m0 + wr * 64 + tm * 16 + (l >> 4) * 4 + r;
                float v = fmaxf(acc[tm][tn][r] + bv, 0.f);
                if constexpr (SPLIT) {
                    unsigned short h = f2bf(v);
                    Chi[(size_t)row * N + col] = h;
                    Clo[(size_t)row * N + col] = f2bf(v - bf2f(h));
                } else {
                    Cf[(size_t)row * N + col] = v;
                }
            }
        }
    }
}

// ---------------------------------------------------------------- last layer + log_softmax
__global__ __launch_bounds__(256) void last_layer_kernel(
    const float* __restrict__ A, const float* __restrict__ W,
    const float* __restrict__ b, float* __restrict__ out, int N) {
    constexpr int KD = 128, NC = 13;
    __shared__ float ws[KD * NC];
    __shared__ float bs[NC];
    const int tid = threadIdx.x;
    for (int idx = tid; idx < KD * NC; idx += 256) ws[idx] = W[idx];
    if (tid < NC) bs[tid] = b[tid];
    __syncthreads();
    int r = blockIdx.x * 256 + tid;
    if (r >= N) return;
    float acc[NC];
#pragma unroll
    for (int f = 0; f < NC; ++f) acc[f] = bs[f];
    const float4* row = reinterpret_cast<const float4*>(A + (size_t)r * KD);
#pragma unroll 4
    for (int c4 = 0; c4 < KD / 4; ++c4) {
        float4 v = row[c4];
#pragma unroll
        for (int f = 0; f < NC; ++f) acc[f] += v.x * ws[(c4 * 4 + 0) * NC + f];
#pragma unroll
        for (int f = 0; f < NC; ++f) acc[f] += v.y * ws[(c4 * 4 + 1) * NC + f];
#pragma unroll
        for (int f = 0; f < NC; ++f) acc[f] += v.z * ws[(c4 * 4 + 2) * NC + f];
#pragma unroll
        for (int f = 0; f < NC; ++f) acc[f] += v.w * ws[(c4 * 4 + 3) * NC + f];
    }
    float m = acc[0];
#pragma unroll
    for (int f = 1; f < NC; ++f) m = fmaxf(m, acc[f]);
    float s = 0.f;
#pragma unroll
    for (int f = 0; f < NC; ++f) s += expf(acc[f] - m);
    float ls = logf(s);
#pragma unroll
    for (int f = 0; f < NC; ++f) out[(size_t)r * NC + f] = acc[f] - m - ls;
}

// ---------------------------------------------------------------- launch
extern "C" void kernel_launch(void* const* d_in, const int* in_sizes, int n_in,
                              void* d_out, int out_size, void* d_ws, size_t ws_size,
                              hipStream_t stream) {
    const float* x   = (const float*)d_in[0];
    const float* w1  = (const float*)d_in[1];
    const float* b1  = (const float*)d_in[2];
    const float* w2  = (const float*)d_in[3];
    const float* b2  = (const float*)d_in[4];
    const float* w3  = (const float*)d_in[5];
    const float* b3  = (const float*)d_in[6];
    const float* wl1 = (const float*)d_in[7];
    const float* bl1 = (const float*)d_in[8];
    const float* wm1 = (const float*)d_in[9];
    const float* bm1 = (const float*)d_in[10];
    const float* wm2 = (const float*)d_in[11];
    const float* bm2 = (const float*)d_in[12];
    const float* wm3 = (const float*)d_in[13];
    const float* bm3 = (const float*)d_in[14];
    float* out = (float*)d_out;

    const int N = in_sizes[0] / 3;  // 8192
    const int NCH = N / CHSZ;       // 4 chunks

    float* ws = (float*)d_ws;
    size_t off = 0;
    auto alloc = [&](size_t n) { float* p = ws + off; off += n; return p; };
    float* sq  = alloc(N);
    int*   nbr = (int*)alloc((size_t)N * KNN);
    float* x1  = alloc((size_t)N * 64);
    float* x2  = alloc((size_t)N * 64);
    float* x3  = alloc((size_t)N * 64);
    float* AB  = alloc((size_t)N * 128);
    float* WW  = alloc(64 * 128);
    float* bb  = alloc(128);
    float* sd  = alloc((size_t)N * KNN);
    int*   si  = (int*)alloc((size_t)N * KNN);
    unsigned short* bt1 = (unsigned short*)alloc((size_t)1024 * 576 / 2);   // [1024][576]
    unsigned short* bt2 = (unsigned short*)alloc((size_t)256 * 3072 / 2);   // [256][3072]
    unsigned short* bt3 = (unsigned short*)alloc((size_t)128 * 768 / 2);    // [128][768]
    // union region: D chunk (knn phase) vs head activations (head phase)
    size_t dsz = (size_t)N * CHSZ;  // 16.8M floats > head usage (13.1M)
    float* Z = alloc(dsz);
    float* D = Z;
    unsigned short* cat_hi = (unsigned short*)Z;
    unsigned short* cat_lo = cat_hi + (size_t)N * 192;
    unsigned short* a1_hi  = cat_lo + (size_t)N * 192;
    unsigned short* a1_lo  = a1_hi + (size_t)N * 1024;
    unsigned short* a2_hi  = a1_lo + (size_t)N * 1024;
    unsigned short* a2_lo  = a2_hi + (size_t)N * 256;
    float* a3 = (float*)(a2_lo + (size_t)N * 256);

    // ---- stage 1 (C=3)
    rowsq_kernel<3><<<N / 256, 256, 0, stream>>>(x, sq, N);
    for (int c = 0; c < NCH; ++c) {
        dist3_kernel<<<(size_t)N * CHSZ / 4 / 256, 256, 0, stream>>>(x, sq, D, N, c * CHSZ);
        knn_select_kernel<<<N / 4, 256, 0, stream>>>(D, sd, si, nbr, c * CHSZ, c == 0, c == NCH - 1);
    }
    prep_w_kernel<3><<<2, 256, 0, stream>>>(w1, b1, WW, bb);
    ec_gemm_kernel<3><<<N / 32, 128, 0, stream>>>(x, WW, bb, AB, N);
    ec_max_kernel<<<N / 4, 256, 0, stream>>>(AB, nbr, x1, N);
    // ---- stage 2 (C=64)
    rowsq_kernel<64><<<N / 256, 256, 0, stream>>>(x1, sq, N);
    for (int c = 0; c < NCH; ++c) {
        dist_gemm_kernel<<<dim3(CHSZ / 128, N / 128), 256, 0, stream>>>(x1, sq, D, N, c * CHSZ);
        knn_select_kernel<<<N / 4, 256, 0, stream>>>(D, sd, si, nbr, c * CHSZ, c == 0, c == NCH - 1);
    }
    prep_w_kernel<64><<<32, 256, 0, stream>>>(w2, b2, WW, bb);
    ec_gemm_kernel<64><<<N / 32, 128, 0, stream>>>(x1, WW, bb, AB, N);
    ec_max_kernel<<<N / 4, 256, 0, stream>>>(AB, nbr, x2, N);
    // ---- stage 3 (C=64)
    rowsq_kernel<64><<<N / 256, 256, 0, stream>>>(x2, sq, N);
    for (int c = 0; c < NCH; ++c) {
        dist_gemm_kernel<<<dim3(CHSZ / 128, N / 128), 256, 0, stream>>>(x2, sq, D, N, c * CHSZ);
        knn_select_kernel<<<N / 4, 256, 0, stream>>>(D, sd, si, nbr, c * CHSZ, c == 0, c == NCH - 1);
    }
    prep_w_kernel<64><<<32, 256, 0, stream>>>(w3, b3, WW, bb);
    ec_gemm_kernel<64><<<N / 32, 128, 0, stream>>>(x2, WW, bb, AB, N);
    ec_max_kernel<<<N / 4, 256, 0, stream>>>(AB, nbr, x3, N);
    // ---- MLP head (split-bf16 MFMA)
    prep_bsplit_kernel<<<(1024 * 576 + 255) / 256, 256, 0, stream>>>(wl1, bt1, 192, 1024);
    prep_bsplit_kernel<<<(256 * 3072 + 255) / 256, 256, 0, stream>>>(wm1, bt2, 1024, 256);
    prep_bsplit_kernel<<<(128 * 768 + 255) / 256, 256, 0, stream>>>(wm2, bt3, 256, 128);
    concat_split_kernel<<<(N * 192 + 255) / 256, 256, 0, stream>>>(x1, x2, x3, cat_hi, cat_lo, N);
    mfma_gemm_kernel<128, 128, 1><<<dim3(1024 / 128, N / 128), 256, 0, stream>>>(
        cat_hi, cat_lo, bt1, bl1, nullptr, a1_hi, a1_lo, N, 1024, 192);
    mfma_gemm_kernel<256, 64, 1><<<dim3(256 / 64, N / 256), 256, 0, stream>>>(
        a1_hi, a1_lo, bt2, bm1, nullptr, a2_hi, a2_lo, N, 256, 1024);
    mfma_gemm_kernel<256, 64, 0><<<dim3(128 / 64, N / 256), 256, 0, stream>>>(
        a2_hi, a2_lo, bt3, bm2, a3, nullptr, nullptr, N, 128, 256);
    last_layer_kernel<<<(N + 255) / 256, 256, 0, stream>>>(a3, wm3, bm3, out, N);
}

// Round 5
// 973.621 us; speedup vs baseline: 5.7635x; 1.0908x over previous
//
#include <hip/hip_runtime.h>
#include <hip/hip_bf16.h>
#include <math.h>

#define KNN 20
#define CHSZ 2048   // candidate chunk size for distance matrix

typedef __attribute__((ext_vector_type(8))) short bf16x8_t;
typedef __attribute__((ext_vector_type(4))) float f32x4_t;

// bf16 split helpers (RNE)
__device__ __forceinline__ unsigned short f2bf(float f) {
    unsigned u = __float_as_uint(f);
    u += 0x7fffu + ((u >> 16) & 1u);
    return (unsigned short)(u >> 16);
}
__device__ __forceinline__ float bf2f(unsigned short h) {
    return __uint_as_float((unsigned)h << 16);
}

// async global->LDS, 16 B per lane; dest = wave-uniform base + lane*16
__device__ __forceinline__ void gload_lds16(const void* g, void* l) {
    auto gp = reinterpret_cast<const __attribute__((address_space(1))) unsigned*>(
        reinterpret_cast<uintptr_t>(g));
    auto lp = reinterpret_cast<__attribute__((address_space(3))) unsigned*>(
        reinterpret_cast<uintptr_t>(l));
    __builtin_amdgcn_global_load_lds(gp, lp, 16, 0, 0);
}

// ---------------------------------------------------------------- rowsq
template<int C>
__global__ void rowsq_kernel(const float* __restrict__ x, float* __restrict__ sq, int N) {
    int i = blockIdx.x * blockDim.x + threadIdx.x;
    if (i >= N) return;
    float s = 0.f;
    if constexpr (C == 64) {
        const float4* p = reinterpret_cast<const float4*>(x + (size_t)i * C);
#pragma unroll
        for (int c = 0; c < 16; ++c) {
            float4 v = p[c];
            s += v.x * v.x + v.y * v.y + v.z * v.z + v.w * v.w;
        }
    } else {
#pragma unroll
        for (int c = 0; c < C; ++c) { float v = x[(size_t)i * C + c]; s += v * v; }
    }
    sq[i] = s;
}

// ---------------------------------------------------------------- dist GEMM (C=64, fp32 exact)
__global__ __launch_bounds__(256, 2) void dist_gemm_kernel(
    const float* __restrict__ X, const float* __restrict__ sq,
    float* __restrict__ D, int N, int chunk_base) {
    constexpr int K = 64, BK = 8, ST = 132;
    __shared__ float As[BK * ST];
    __shared__ float Bs[BK * ST];
    const int tid = threadIdx.x;
    const int tx = tid & 15, ty = tid >> 4;
    const int m0 = blockIdx.y * 128;
    const int n0 = blockIdx.x * 128;
    const int jb = chunk_base + n0;
    const int sr = tid >> 1, skq = tid & 1;

    float acc[8][8] = {};

    for (int k0 = 0; k0 < K; k0 += BK) {
        float4 va = *reinterpret_cast<const float4*>(X + (size_t)(m0 + sr) * K + k0 + 4 * skq);
        float4 vb = *reinterpret_cast<const float4*>(X + (size_t)(jb + sr) * K + k0 + 4 * skq);
        As[(4 * skq + 0) * ST + sr] = va.x;
        As[(4 * skq + 1) * ST + sr] = va.y;
        As[(4 * skq + 2) * ST + sr] = va.z;
        As[(4 * skq + 3) * ST + sr] = va.w;
        Bs[(4 * skq + 0) * ST + sr] = vb.x;
        Bs[(4 * skq + 1) * ST + sr] = vb.y;
        Bs[(4 * skq + 2) * ST + sr] = vb.z;
        Bs[(4 * skq + 3) * ST + sr] = vb.w;
        __syncthreads();
#pragma unroll
        for (int kk = 0; kk < BK; ++kk) {
            float4 alo = *reinterpret_cast<const float4*>(&As[kk * ST + ty * 4]);
            float4 ahi = *reinterpret_cast<const float4*>(&As[kk * ST + 64 + ty * 4]);
            float4 blo = *reinterpret_cast<const float4*>(&Bs[kk * ST + tx * 4]);
            float4 bhi = *reinterpret_cast<const float4*>(&Bs[kk * ST + 64 + tx * 4]);
            float a[8] = {alo.x, alo.y, alo.z, alo.w, ahi.x, ahi.y, ahi.z, ahi.w};
            float b[8] = {blo.x, blo.y, blo.z, blo.w, bhi.x, bhi.y, bhi.z, bhi.w};
#pragma unroll
            for (int u = 0; u < 8; ++u)
#pragma unroll
                for (int v = 0; v < 8; ++v) acc[u][v] += a[u] * b[v];
        }
        __syncthreads();
    }

    int mm[8], jn[8];
    float sm[8], sn[8];
#pragma unroll
    for (int u = 0; u < 8; ++u) {
        mm[u] = m0 + (u < 4 ? ty * 4 + u : 64 + ty * 4 + (u - 4));
        sm[u] = sq[mm[u]];
    }
#pragma unroll
    for (int v = 0; v < 8; ++v) {
        int nn = (v < 4 ? tx * 4 + v : 64 + tx * 4 + (v - 4));
        jn[v] = jb + nn;
        sn[v] = sq[jn[v]];
    }
#pragma unroll
    for (int u = 0; u < 8; ++u) {
        float4 lo, hi;
        float* lp = &lo.x; float* hp = &hi.x;
#pragma unroll
        for (int v = 0; v < 4; ++v) {
            float val = sm[u] + sn[v] - 2.f * acc[u][v];
            if (mm[u] == jn[v]) val = INFINITY;
            lp[v] = val;
        }
#pragma unroll
        for (int v = 4; v < 8; ++v) {
            float val = sm[u] + sn[v] - 2.f * acc[u][v];
            if (mm[u] == jn[v]) val = INFINITY;
            hp[v - 4] = val;
        }
        *reinterpret_cast<float4*>(D + (size_t)mm[u] * CHSZ + n0 + tx * 4) = lo;
        *reinterpret_cast<float4*>(D + (size_t)mm[u] * CHSZ + n0 + 64 + tx * 4) = hi;
    }
}

// ---------------------------------------------------------------- knn select (C=64 path)
// One wave per point. Running top-20 distributed one entry per lane (lanes
// 0..19), sorted ascending by lex (dist, idx) == jax.lax.top_k tie-break.
// All 8 row-loads issued upfront (independent -> one latency exposure),
// then filtered; insertion via ballot-rank + shfl_up (rare).
__global__ __launch_bounds__(256) void knn_select_kernel(
    const float* __restrict__ D, float* __restrict__ sd, int* __restrict__ si,
    int* __restrict__ nbrs, int chunk_base, int first, int last) {
    const int tid = threadIdx.x;
    const int w = tid >> 6, l = tid & 63;
    const int p = blockIdx.x * 4 + w;

    float dl = INFINITY; int il = 0x7fffffff;
    if (!first && l < KNN) { dl = sd[(size_t)p * KNN + l]; il = si[(size_t)p * KNN + l]; }
    float td = __shfl(dl, 19); int ti = __shfl(il, 19);

    const float4* Drow = reinterpret_cast<const float4*>(D + (size_t)p * CHSZ);
    float4 v[8];
#pragma unroll
    for (int b = 0; b < 8; ++b) v[b] = Drow[b * 64 + l];

#pragma unroll
    for (int b = 0; b < 8; ++b) {
        bool q0 = v[b].x <= td, q1 = v[b].y <= td, q2 = v[b].z <= td, q3 = v[b].w <= td;
        unsigned long long anyb = __ballot(q0 | q1 | q2 | q3);
        if (!anyb) continue;
#pragma unroll
        for (int qq = 0; qq < 4; ++qq) {
            float vq = (qq == 0) ? v[b].x : (qq == 1) ? v[b].y : (qq == 2) ? v[b].z : v[b].w;
            unsigned long long bal = __ballot((qq == 0) ? q0 : (qq == 1) ? q1 : (qq == 2) ? q2 : q3);
            while (bal) {
                int ln = __ffsll((unsigned long long)bal) - 1;
                bal &= bal - 1;
                float cv = __shfl(vq, ln);
                int cj = chunk_base + b * 256 + 4 * ln + qq;
                if (cv < td || (cv == td && cj < ti)) {
                    bool cmp = (dl < cv) || (dl == cv && il < cj);
                    unsigned long long cb = __ballot(cmp) & 0xFFFFFull;
                    int r = __popcll(cb);
                    float sdl = __shfl_up(dl, 1);
                    int sil = __shfl_up(il, 1);
                    if (l == r) { dl = cv; il = cj; }
                    else if (l > r && l < KNN) { dl = sdl; il = sil; }
                    td = __shfl(dl, 19); ti = __shfl(il, 19);
                }
            }
        }
    }
    if (l < KNN) {
        sd[(size_t)p * KNN + l] = dl;
        si[(size_t)p * KNN + l] = il;
        if (last) nbrs[(size_t)p * KNN + l] = il;
    }
}

// ---------------------------------------------------------------- knn fused (C=3)
// One wave per point, single dispatch over ALL candidates; distance (3 FMAs)
// computed inline from x (L2-resident) -- no D materialization at all.
__global__ __launch_bounds__(256) void knn3_fused_kernel(
    const float* __restrict__ X, const float* __restrict__ sq,
    int* __restrict__ nbrs, int N) {
    const int tid = threadIdx.x;
    const int w = tid >> 6, l = tid & 63;
    const int p = blockIdx.x * 4 + w;
    const float x0 = X[(size_t)p * 3], x1 = X[(size_t)p * 3 + 1], x2 = X[(size_t)p * 3 + 2];
    const float sp = sq[p];
    float dl = INFINITY; int il = 0x7fffffff;
    float td = INFINITY; int ti = 0x7fffffff;

#pragma unroll 1
    for (int j0 = 0; j0 < N; j0 += 256) {
        const int jl = j0 + 4 * l;
        const float4* xr = reinterpret_cast<const float4*>(X + (size_t)jl * 3);
        float4 r0 = xr[0], r1 = xr[1], r2 = xr[2];
        float4 sj = *reinterpret_cast<const float4*>(sq + jl);
        float v0 = sp + sj.x - 2.f * (x0 * r0.x + x1 * r0.y + x2 * r0.z);
        float v1 = sp + sj.y - 2.f * (x0 * r0.w + x1 * r1.x + x2 * r1.y);
        float v2 = sp + sj.z - 2.f * (x0 * r1.z + x1 * r1.w + x2 * r2.x);
        float v3 = sp + sj.w - 2.f * (x0 * r2.y + x1 * r2.z + x2 * r2.w);
        if (jl + 0 == p) v0 = INFINITY;
        if (jl + 1 == p) v1 = INFINITY;
        if (jl + 2 == p) v2 = INFINITY;
        if (jl + 3 == p) v3 = INFINITY;
        bool q0 = v0 <= td, q1 = v1 <= td, q2 = v2 <= td, q3 = v3 <= td;
        unsigned long long anyb = __ballot(q0 | q1 | q2 | q3);
        if (!anyb) continue;
#pragma unroll
        for (int qq = 0; qq < 4; ++qq) {
            float vq = (qq == 0) ? v0 : (qq == 1) ? v1 : (qq == 2) ? v2 : v3;
            unsigned long long bal = __ballot((qq == 0) ? q0 : (qq == 1) ? q1 : (qq == 2) ? q2 : q3);
            while (bal) {
                int ln = __ffsll((unsigned long long)bal) - 1;
                bal &= bal - 1;
                float cv = __shfl(vq, ln);
                int cj = j0 + 4 * ln + qq;
                if (cv < td || (cv == td && cj < ti)) {
                    bool cmp = (dl < cv) || (dl == cv && il < cj);
                    unsigned long long cb = __ballot(cmp) & 0xFFFFFull;
                    int r = __popcll(cb);
                    float sdl = __shfl_up(dl, 1);
                    int sil = __shfl_up(il, 1);
                    if (l == r) { dl = cv; il = cj; }
                    else if (l > r && l < KNN) { dl = sdl; il = sil; }
                    td = __shfl(dl, 19); ti = __shfl(il, 19);
                }
            }
        }
    }
    if (l < KNN) nbrs[(size_t)p * KNN + l] = il;
}

// ---------------------------------------------------------------- edgeconv (factored, fp32 exact)
template<int C>
__global__ void prep_w_kernel(const float* __restrict__ w, const float* __restrict__ b,
                              float* __restrict__ WW, float* __restrict__ bb) {
    int t = blockIdx.x * blockDim.x + threadIdx.x;
    if (t < 128) bb[t] = (t < 64) ? b[t] : 0.f;
    if (t >= C * 128) return;
    int c = t >> 7, f = t & 127;
    WW[t] = (f < 64) ? (w[c * 64 + f] - w[(C + c) * 64 + f]) : w[(C + c) * 64 + (f - 64)];
}

template<int C>
__global__ __launch_bounds__(128) void ec_gemm_kernel(
    const float* __restrict__ x, const float* __restrict__ WW,
    const float* __restrict__ bb, float* __restrict__ AB, int N) {
    __shared__ float Ws[C * 128];
    __shared__ float xs[32 * C];
    const int tid = threadIdx.x;
    const int r0 = blockIdx.x * 32;
    for (int idx = tid; idx < C * 128; idx += 128) Ws[idx] = WW[idx];
    for (int idx = tid; idx < 32 * C; idx += 128) xs[idx] = x[(size_t)r0 * C + idx];
    __syncthreads();
    const float bias = bb[tid];
#pragma unroll 1
    for (int r = 0; r < 32; ++r) {
        float acc = bias;
#pragma unroll
        for (int c = 0; c < C; ++c) acc = fmaf(xs[r * C + c], Ws[c * 128 + tid], acc);
        AB[(size_t)(r0 + r) * 128 + tid] = acc;
    }
}

__global__ __launch_bounds__(256) void ec_max_kernel(
    const float* __restrict__ AB, const int* __restrict__ nbrs,
    float* __restrict__ out, int N) {
    const int tid = threadIdx.x;
    const int w = tid >> 6, f = tid & 63;
    const int i = blockIdx.x * 4 + w;
    const float a = AB[(size_t)i * 128 + f];
    const int* nb = nbrs + (size_t)i * KNN;
    float m = -3.4e38f;
#pragma unroll
    for (int j = 0; j < KNN; ++j) {
        int n = nb[j];
        m = fmaxf(m, AB[(size_t)n * 128 + 64 + f]);
    }
    out[(size_t)i * 64 + f] = fmaxf(a + m, 0.f);
}

// ---------------------------------------------------------------- concat + split to bf16 hi/lo
__global__ void concat_split_kernel(const float* __restrict__ a, const float* __restrict__ b,
                                    const float* __restrict__ c,
                                    unsigned short* __restrict__ hi, unsigned short* __restrict__ lo,
                                    int N) {
    int t = blockIdx.x * blockDim.x + threadIdx.x;
    if (t >= N * 192) return;
    int r = t / 192, cc = t % 192;
    float v;
    if (cc < 64) v = a[(size_t)r * 64 + cc];
    else if (cc < 128) v = b[(size_t)r * 64 + cc - 64];
    else v = c[(size_t)r * 64 + cc - 128];
    unsigned short h = f2bf(v);
    hi[t] = h;
    lo[t] = f2bf(v - bf2f(h));
}

// ---------------------------------------------------------------- weight split: BT[F][3K]
__global__ void prep_bsplit_kernel(const float* __restrict__ W, unsigned short* __restrict__ BT,
                                   int K, int F) {
    int t = blockIdx.x * 256 + threadIdx.x;
    int K3 = 3 * K;
    if (t >= F * K3) return;
    int n = t / K3, kp = t - n * K3;
    int seg = kp / K;
    int k = kp - seg * K;
    float v = W[(size_t)k * F + n];
    unsigned short h = f2bf(v);
    BT[t] = (seg == 1) ? f2bf(v - bf2f(h)) : h;
}

// ---------------------------------------------------------------- split-bf16 MFMA GEMM
template<int BM, int BN, int SPLIT>
__global__ __launch_bounds__(256) void mfma_gemm_kernel(
    const unsigned short* __restrict__ Ahi, const unsigned short* __restrict__ Alo,
    const unsigned short* __restrict__ BT, const float* __restrict__ bias,
    float* __restrict__ Cf, unsigned short* __restrict__ Chi, unsigned short* __restrict__ Clo,
    int M, int N, int K) {
    constexpr int WR = BM / 64, WC = BN / 64;
    static_assert(WR * WC == 4, "4 waves");
    __shared__ __align__(16) unsigned short As[BM * 64];
    __shared__ __align__(16) unsigned short Bs[BN * 64];
    const int tid = threadIdx.x;
    const int w = tid >> 6, l = tid & 63;
    const int wr = w % WR, wc = w / WR;
    const int m0 = blockIdx.y * BM, n0 = blockIdx.x * BN;
    const int K3 = 3 * K;

    f32x4_t acc[4][4];
#pragma unroll
    for (int a = 0; a < 4; ++a)
#pragma unroll
        for (int b = 0; b < 4; ++b) acc[a][b] = (f32x4_t){0.f, 0.f, 0.f, 0.f};

    const int lr = l >> 3;
    const int swz = ((l & 7) ^ lr) * 8;
    const int frow = l & 15;
    const int fq = l >> 4;
    const int fswz = l & 7;

    for (int kt = 0; kt < K3 / 64; ++kt) {
        const int kk = kt * 64;
        const unsigned short* srcA; int k0;
        if (kk < K)            { srcA = Ahi; k0 = kk; }
        else if (kk < 2 * K)   { srcA = Ahi; k0 = kk - K; }
        else                   { srcA = Alo; k0 = kk - 2 * K; }
#pragma unroll
        for (int t = 0; t < BM / 32; ++t) {
            int row = w * (BM / 4) + t * 8;
            gload_lds16(srcA + (size_t)(m0 + row + lr) * K + k0 + swz,
                        (void*)(As + row * 64));
        }
#pragma unroll
        for (int t = 0; t < BN / 32; ++t) {
            int row = w * (BN / 4) + t * 8;
            gload_lds16(BT + (size_t)(n0 + row + lr) * K3 + kk + swz,
                        (void*)(Bs + row * 64));
        }
        __syncthreads();
#pragma unroll
        for (int ks = 0; ks < 2; ++ks) {
            bf16x8_t af[4], bf[4];
            const int o = (ks * 4 + fq) ^ fswz;
#pragma unroll
            for (int tm = 0; tm < 4; ++tm) {
                int row = wr * 64 + tm * 16 + frow;
                af[tm] = *reinterpret_cast<const bf16x8_t*>(As + row * 64 + o * 8);
            }
#pragma unroll
            for (int tn = 0; tn < 4; ++tn) {
                int row = wc * 64 + tn * 16 + frow;
                bf[tn] = *reinterpret_cast<const bf16x8_t*>(Bs + row * 64 + o * 8);
            }
#pragma unroll
            for (int tm = 0; tm < 4; ++tm)
#pragma unroll
                for (int tn = 0; tn < 4; ++tn)
                    acc[tm][tn] = __builtin_amdgcn_mfma_f32_16x16x32_bf16(
                        af[tm], bf[tn], acc[tm][tn], 0, 0, 0);
        }
        __syncthreads();
    }

#pragma unroll
    for (int tn = 0; tn < 4; ++tn) {
        int col = n0 + wc * 64 + tn * 16 + (l & 15);
        float bv = bias[col];
#pragma unroll
        for (int tm = 0; tm < 4; ++tm) {
#pragma unroll
            for (int r = 0; r < 4; ++r) {
                int row = m0 + wr * 64 + tm * 16 + (l >> 4) * 4 + r;
                float v = fmaxf(acc[tm][tn][r] + bv, 0.f);
                if constexpr (SPLIT) {
                    unsigned short h = f2bf(v);
                    Chi[(size_t)row * N + col] = h;
                    Clo[(size_t)row * N + col] = f2bf(v - bf2f(h));
                } else {
                    Cf[(size_t)row * N + col] = v;
                }
            }
        }
    }
}

// ---------------------------------------------------------------- last layer + log_softmax
__global__ __launch_bounds__(256) void last_layer_kernel(
    const float* __restrict__ A, const float* __restrict__ W,
    const float* __restrict__ b, float* __restrict__ out, int N) {
    constexpr int KD = 128, NC = 13;
    __shared__ float ws[KD * NC];
    __shared__ float bs[NC];
    const int tid = threadIdx.x;
    for (int idx = tid; idx < KD * NC; idx += 256) ws[idx] = W[idx];
    if (tid < NC) bs[tid] = b[tid];
    __syncthreads();
    int r = blockIdx.x * 256 + tid;
    if (r >= N) return;
    float acc[NC];
#pragma unroll
    for (int f = 0; f < NC; ++f) acc[f] = bs[f];
    const float4* row = reinterpret_cast<const float4*>(A + (size_t)r * KD);
#pragma unroll 4
    for (int c4 = 0; c4 < KD / 4; ++c4) {
        float4 v = row[c4];
#pragma unroll
        for (int f = 0; f < NC; ++f) acc[f] += v.x * ws[(c4 * 4 + 0) * NC + f];
#pragma unroll
        for (int f = 0; f < NC; ++f) acc[f] += v.y * ws[(c4 * 4 + 1) * NC + f];
#pragma unroll
        for (int f = 0; f < NC; ++f) acc[f] += v.z * ws[(c4 * 4 + 2) * NC + f];
#pragma unroll
        for (int f = 0; f < NC; ++f) acc[f] += v.w * ws[(c4 * 4 + 3) * NC + f];
    }
    float m = acc[0];
#pragma unroll
    for (int f = 1; f < NC; ++f) m = fmaxf(m, acc[f]);
    float s = 0.f;
#pragma unroll
    for (int f = 0; f < NC; ++f) s += expf(acc[f] - m);
    float ls = logf(s);
#pragma unroll
    for (int f = 0; f < NC; ++f) out[(size_t)r * NC + f] = acc[f] - m - ls;
}

// ---------------------------------------------------------------- launch
extern "C" void kernel_launch(void* const* d_in, const int* in_sizes, int n_in,
                              void* d_out, int out_size, void* d_ws, size_t ws_size,
                              hipStream_t stream) {
    const float* x   = (const float*)d_in[0];
    const float* w1  = (const float*)d_in[1];
    const float* b1  = (const float*)d_in[2];
    const float* w2  = (const float*)d_in[3];
    const float* b2  = (const float*)d_in[4];
    const float* w3  = (const float*)d_in[5];
    const float* b3  = (const float*)d_in[6];
    const float* wl1 = (const float*)d_in[7];
    const float* bl1 = (const float*)d_in[8];
    const float* wm1 = (const float*)d_in[9];
    const float* bm1 = (const float*)d_in[10];
    const float* wm2 = (const float*)d_in[11];
    const float* bm2 = (const float*)d_in[12];
    const float* wm3 = (const float*)d_in[13];
    const float* bm3 = (const float*)d_in[14];
    float* out = (float*)d_out;

    const int N = in_sizes[0] / 3;  // 8192
    const int NCH = N / CHSZ;       // 4 chunks

    float* ws = (float*)d_ws;
    size_t off = 0;
    auto alloc = [&](size_t n) { float* p = ws + off; off += n; return p; };
    float* sq  = alloc(N);
    int*   nbr = (int*)alloc((size_t)N * KNN);
    float* x1  = alloc((size_t)N * 64);
    float* x2  = alloc((size_t)N * 64);
    float* x3  = alloc((size_t)N * 64);
    float* AB  = alloc((size_t)N * 128);
    float* WW  = alloc(64 * 128);
    float* bb  = alloc(128);
    float* sd  = alloc((size_t)N * KNN);
    int*   si  = (int*)alloc((size_t)N * KNN);
    unsigned short* bt1 = (unsigned short*)alloc((size_t)1024 * 576 / 2);   // [1024][576]
    unsigned short* bt2 = (unsigned short*)alloc((size_t)256 * 3072 / 2);   // [256][3072]
    unsigned short* bt3 = (unsigned short*)alloc((size_t)128 * 768 / 2);    // [128][768]
    // union region: D chunk (knn phase) vs head activations (head phase)
    size_t dsz = (size_t)N * CHSZ;  // 16.8M floats > head usage (13.1M)
    float* Z = alloc(dsz);
    float* D = Z;
    unsigned short* cat_hi = (unsigned short*)Z;
    unsigned short* cat_lo = cat_hi + (size_t)N * 192;
    unsigned short* a1_hi  = cat_lo + (size_t)N * 192;
    unsigned short* a1_lo  = a1_hi + (size_t)N * 1024;
    unsigned short* a2_hi  = a1_lo + (size_t)N * 1024;
    unsigned short* a2_lo  = a2_hi + (size_t)N * 256;
    float* a3 = (float*)(a2_lo + (size_t)N * 256);

    // ---- stage 1 (C=3): fused dist+select, single dispatch
    rowsq_kernel<3><<<N / 256, 256, 0, stream>>>(x, sq, N);
    knn3_fused_kernel<<<N / 4, 256, 0, stream>>>(x, sq, nbr, N);
    prep_w_kernel<3><<<2, 256, 0, stream>>>(w1, b1, WW, bb);
    ec_gemm_kernel<3><<<N / 32, 128, 0, stream>>>(x, WW, bb, AB, N);
    ec_max_kernel<<<N / 4, 256, 0, stream>>>(AB, nbr, x1, N);
    // ---- stage 2 (C=64)
    rowsq_kernel<64><<<N / 256, 256, 0, stream>>>(x1, sq, N);
    for (int c = 0; c < NCH; ++c) {
        dist_gemm_kernel<<<dim3(CHSZ / 128, N / 128), 256, 0, stream>>>(x1, sq, D, N, c * CHSZ);
        knn_select_kernel<<<N / 4, 256, 0, stream>>>(D, sd, si, nbr, c * CHSZ, c == 0, c == NCH - 1);
    }
    prep_w_kernel<64><<<32, 256, 0, stream>>>(w2, b2, WW, bb);
    ec_gemm_kernel<64><<<N / 32, 128, 0, stream>>>(x1, WW, bb, AB, N);
    ec_max_kernel<<<N / 4, 256, 0, stream>>>(AB, nbr, x2, N);
    // ---- stage 3 (C=64)
    rowsq_kernel<64><<<N / 256, 256, 0, stream>>>(x2, sq, N);
    for (int c = 0; c < NCH; ++c) {
        dist_gemm_kernel<<<dim3(CHSZ / 128, N / 128), 256, 0, stream>>>(x2, sq, D, N, c * CHSZ);
        knn_select_kernel<<<N / 4, 256, 0, stream>>>(D, sd, si, nbr, c * CHSZ, c == 0, c == NCH - 1);
    }
    prep_w_kernel<64><<<32, 256, 0, stream>>>(w3, b3, WW, bb);
    ec_gemm_kernel<64><<<N / 32, 128, 0, stream>>>(x2, WW, bb, AB, N);
    ec_max_kernel<<<N / 4, 256, 0, stream>>>(AB, nbr, x3, N);
    // ---- MLP head (split-bf16 MFMA)
    prep_bsplit_kernel<<<(1024 * 576 + 255) / 256, 256, 0, stream>>>(wl1, bt1, 192, 1024);
    prep_bsplit_kernel<<<(256 * 3072 + 255) / 256, 256, 0, stream>>>(wm1, bt2, 1024, 256);
    prep_bsplit_kernel<<<(128 * 768 + 255) / 256, 256, 0, stream>>>(wm2, bt3, 256, 128);
    concat_split_kernel<<<(N * 192 + 255) / 256, 256, 0, stream>>>(x1, x2, x3, cat_hi, cat_lo, N);
    mfma_gemm_kernel<128, 128, 1><<<dim3(1024 / 128, N / 128), 256, 0, stream>>>(
        cat_hi, cat_lo, bt1, bl1, nullptr, a1_hi, a1_lo, N, 1024, 192);
    mfma_gemm_kernel<256, 64, 1><<<dim3(256 / 64, N / 256), 256, 0, stream>>>(
        a1_hi, a1_lo, bt2, bm1, nullptr, a2_hi, a2_lo, N, 256, 1024);
    mfma_gemm_kernel<256, 64, 0><<<dim3(128 / 64, N / 256), 256, 0, stream>>>(
        a2_hi, a2_lo, bt3, bm2, a3, nullptr, nullptr, N, 128, 256);
    last_layer_kernel<<<(N + 255) / 256, 256, 0, stream>>>(a3, wm3, bm3, out, N);
}

// Round 6
// 765.425 us; speedup vs baseline: 7.3311x; 1.2720x over previous
//
#include <hip/hip_runtime.h>
#include <hip/hip_bf16.h>
#include <math.h>

#define KNN 20
#define CHSZ 2048   // candidate chunk size for distance matrix

typedef __attribute__((ext_vector_type(8))) short bf16x8_t;
typedef __attribute__((ext_vector_type(4))) float f32x4_t;

// bf16 split helpers (RNE)
__device__ __forceinline__ unsigned short f2bf(float f) {
    unsigned u = __float_as_uint(f);
    u += 0x7fffu + ((u >> 16) & 1u);
    return (unsigned short)(u >> 16);
}
__device__ __forceinline__ float bf2f(unsigned short h) {
    return __uint_as_float((unsigned)h << 16);
}

// async global->LDS, 16 B per lane; dest = wave-uniform base + lane*16
__device__ __forceinline__ void gload_lds16(const void* g, void* l) {
    auto gp = reinterpret_cast<const __attribute__((address_space(1))) unsigned*>(
        reinterpret_cast<uintptr_t>(g));
    auto lp = reinterpret_cast<__attribute__((address_space(3))) unsigned*>(
        reinterpret_cast<uintptr_t>(l));
    __builtin_amdgcn_global_load_lds(gp, lp, 16, 0, 0);
}

// 64-lane bitonic ascending sort of one float per lane; returns lane-19 value.
// Used to seed the top-20 filter threshold: the 20th order statistic of any
// subset (here: 64 lane-minima) is >= the full set's 20th -> valid filter.
__device__ __forceinline__ float seed_tau(float mv, int l) {
#pragma unroll
    for (int k = 2; k <= 64; k <<= 1) {
#pragma unroll
        for (int j = k >> 1; j > 0; j >>= 1) {
            float o = __shfl_xor(mv, j);
            bool keepMin = (((l & j) == 0) == ((l & k) == 0));
            mv = keepMin ? fminf(mv, o) : fmaxf(mv, o);
        }
    }
    return __shfl(mv, 19);
}

// ---------------------------------------------------------------- rowsq
template<int C>
__global__ void rowsq_kernel(const float* __restrict__ x, float* __restrict__ sq, int N) {
    int i = blockIdx.x * blockDim.x + threadIdx.x;
    if (i >= N) return;
    float s = 0.f;
    if constexpr (C == 64) {
        const float4* p = reinterpret_cast<const float4*>(x + (size_t)i * C);
#pragma unroll
        for (int c = 0; c < 16; ++c) {
            float4 v = p[c];
            s += v.x * v.x + v.y * v.y + v.z * v.z + v.w * v.w;
        }
    } else {
#pragma unroll
        for (int c = 0; c < C; ++c) { float v = x[(size_t)i * C + c]; s += v * v; }
    }
    sq[i] = s;
}

// ---------------------------------------------------------------- dist GEMM (C=64, fp32 exact)
__global__ __launch_bounds__(256, 2) void dist_gemm_kernel(
    const float* __restrict__ X, const float* __restrict__ sq,
    float* __restrict__ D, int N, int chunk_base) {
    constexpr int K = 64, BK = 8, ST = 132;
    __shared__ float As[BK * ST];
    __shared__ float Bs[BK * ST];
    const int tid = threadIdx.x;
    const int tx = tid & 15, ty = tid >> 4;
    const int m0 = blockIdx.y * 128;
    const int n0 = blockIdx.x * 128;
    const int jb = chunk_base + n0;
    const int sr = tid >> 1, skq = tid & 1;

    float acc[8][8] = {};

    for (int k0 = 0; k0 < K; k0 += BK) {
        float4 va = *reinterpret_cast<const float4*>(X + (size_t)(m0 + sr) * K + k0 + 4 * skq);
        float4 vb = *reinterpret_cast<const float4*>(X + (size_t)(jb + sr) * K + k0 + 4 * skq);
        As[(4 * skq + 0) * ST + sr] = va.x;
        As[(4 * skq + 1) * ST + sr] = va.y;
        As[(4 * skq + 2) * ST + sr] = va.z;
        As[(4 * skq + 3) * ST + sr] = va.w;
        Bs[(4 * skq + 0) * ST + sr] = vb.x;
        Bs[(4 * skq + 1) * ST + sr] = vb.y;
        Bs[(4 * skq + 2) * ST + sr] = vb.z;
        Bs[(4 * skq + 3) * ST + sr] = vb.w;
        __syncthreads();
#pragma unroll
        for (int kk = 0; kk < BK; ++kk) {
            float4 alo = *reinterpret_cast<const float4*>(&As[kk * ST + ty * 4]);
            float4 ahi = *reinterpret_cast<const float4*>(&As[kk * ST + 64 + ty * 4]);
            float4 blo = *reinterpret_cast<const float4*>(&Bs[kk * ST + tx * 4]);
            float4 bhi = *reinterpret_cast<const float4*>(&Bs[kk * ST + 64 + tx * 4]);
            float a[8] = {alo.x, alo.y, alo.z, alo.w, ahi.x, ahi.y, ahi.z, ahi.w};
            float b[8] = {blo.x, blo.y, blo.z, blo.w, bhi.x, bhi.y, bhi.z, bhi.w};
#pragma unroll
            for (int u = 0; u < 8; ++u)
#pragma unroll
                for (int v = 0; v < 8; ++v) acc[u][v] += a[u] * b[v];
        }
        __syncthreads();
    }

    int mm[8], jn[8];
    float sm[8], sn[8];
#pragma unroll
    for (int u = 0; u < 8; ++u) {
        mm[u] = m0 + (u < 4 ? ty * 4 + u : 64 + ty * 4 + (u - 4));
        sm[u] = sq[mm[u]];
    }
#pragma unroll
    for (int v = 0; v < 8; ++v) {
        int nn = (v < 4 ? tx * 4 + v : 64 + tx * 4 + (v - 4));
        jn[v] = jb + nn;
        sn[v] = sq[jn[v]];
    }
#pragma unroll
    for (int u = 0; u < 8; ++u) {
        float4 lo, hi;
        float* lp = &lo.x; float* hp = &hi.x;
#pragma unroll
        for (int v = 0; v < 4; ++v) {
            float val = sm[u] + sn[v] - 2.f * acc[u][v];
            if (mm[u] == jn[v]) val = INFINITY;
            lp[v] = val;
        }
#pragma unroll
        for (int v = 4; v < 8; ++v) {
            float val = sm[u] + sn[v] - 2.f * acc[u][v];
            if (mm[u] == jn[v]) val = INFINITY;
            hp[v - 4] = val;
        }
        *reinterpret_cast<float4*>(D + (size_t)mm[u] * CHSZ + n0 + tx * 4) = lo;
        *reinterpret_cast<float4*>(D + (size_t)mm[u] * CHSZ + n0 + 64 + tx * 4) = hi;
    }
}

// ---------------------------------------------------------------- knn select (C=64 path)
// One wave per point; distributed sorted top-20 (lanes 0..19), lex (d,idx)
// order == jax.lax.top_k tie-break. Loads pipelined upfront; coarse filter
// threshold seeded (first chunk) from tile-0 lane minima via bitonic.
__global__ __launch_bounds__(256) void knn_select_kernel(
    const float* __restrict__ D, float* __restrict__ sd, int* __restrict__ si,
    int* __restrict__ nbrs, int chunk_base, int first, int last) {
    const int tid = threadIdx.x;
    const int w = tid >> 6, l = tid & 63;
    const int p = blockIdx.x * 4 + w;

    float dl = INFINITY; int il = 0x7fffffff;
    if (!first && l < KNN) { dl = sd[(size_t)p * KNN + l]; il = si[(size_t)p * KNN + l]; }
    float d19 = __shfl(dl, 19); int i19 = __shfl(il, 19);

    const float4* Drow = reinterpret_cast<const float4*>(D + (size_t)p * CHSZ);
    float4 v[8];
#pragma unroll
    for (int b = 0; b < 8; ++b) v[b] = Drow[b * 64 + l];

    float tau = INFINITY;
    if (first) {
        float mv = fminf(fminf(v[0].x, v[0].y), fminf(v[0].z, v[0].w));
        tau = seed_tau(mv, l);
    }
    float tf = fminf(tau, d19);

#pragma unroll
    for (int b = 0; b < 8; ++b) {
        bool q0 = v[b].x <= tf, q1 = v[b].y <= tf, q2 = v[b].z <= tf, q3 = v[b].w <= tf;
        unsigned long long anyb = __ballot(q0 | q1 | q2 | q3);
        if (!anyb) continue;
#pragma unroll
        for (int qq = 0; qq < 4; ++qq) {
            float vq = (qq == 0) ? v[b].x : (qq == 1) ? v[b].y : (qq == 2) ? v[b].z : v[b].w;
            unsigned long long bal = __ballot((qq == 0) ? q0 : (qq == 1) ? q1 : (qq == 2) ? q2 : q3);
            while (bal) {
                int ln = __ffsll((unsigned long long)bal) - 1;
                bal &= bal - 1;
                float cv = __shfl(vq, ln);
                int cj = chunk_base + b * 256 + 4 * ln + qq;
                if (cv < d19 || (cv == d19 && cj < i19)) {
                    bool cmp = (dl < cv) || (dl == cv && il < cj);
                    unsigned long long cb = __ballot(cmp) & 0xFFFFFull;
                    int r = __popcll(cb);
                    float sdl = __shfl_up(dl, 1);
                    int sil = __shfl_up(il, 1);
                    if (l == r) { dl = cv; il = cj; }
                    else if (l > r && l < KNN) { dl = sdl; il = sil; }
                    d19 = __shfl(dl, 19); i19 = __shfl(il, 19);
                    tf = fminf(tau, d19);
                }
            }
        }
    }
    if (l < KNN) {
        sd[(size_t)p * KNN + l] = dl;
        si[(size_t)p * KNN + l] = il;
        if (last) nbrs[(size_t)p * KNN + l] = il;
    }
}

// ---------------------------------------------------------------- knn fused (C=3)
// One wave per point over all candidates; distances inline (L2-resident x).
// Threshold seeded from tile-0 lane minima to kill the initial insert flood.
__global__ __launch_bounds__(256) void knn3_fused_kernel(
    const float* __restrict__ X, const float* __restrict__ sq,
    int* __restrict__ nbrs, int N) {
    const int tid = threadIdx.x;
    const int w = tid >> 6, l = tid & 63;
    const int p = blockIdx.x * 4 + w;
    const float x0 = X[(size_t)p * 3], x1 = X[(size_t)p * 3 + 1], x2 = X[(size_t)p * 3 + 2];
    const float sp = sq[p];
    float dl = INFINITY; int il = 0x7fffffff;
    float d19 = INFINITY; int i19 = 0x7fffffff;
    float tau = INFINITY, tf = INFINITY;

#pragma unroll 1
    for (int j0 = 0; j0 < N; j0 += 256) {
        const int jl = j0 + 4 * l;
        const float4* xr = reinterpret_cast<const float4*>(X + (size_t)jl * 3);
        float4 r0 = xr[0], r1 = xr[1], r2 = xr[2];
        float4 sj = *reinterpret_cast<const float4*>(sq + jl);
        float v0 = sp + sj.x - 2.f * (x0 * r0.x + x1 * r0.y + x2 * r0.z);
        float v1 = sp + sj.y - 2.f * (x0 * r0.w + x1 * r1.x + x2 * r1.y);
        float v2 = sp + sj.z - 2.f * (x0 * r1.z + x1 * r1.w + x2 * r2.x);
        float v3 = sp + sj.w - 2.f * (x0 * r2.y + x1 * r2.z + x2 * r2.w);
        if (jl + 0 == p) v0 = INFINITY;
        if (jl + 1 == p) v1 = INFINITY;
        if (jl + 2 == p) v2 = INFINITY;
        if (jl + 3 == p) v3 = INFINITY;
        if (j0 == 0) {
            float mv = fminf(fminf(v0, v1), fminf(v2, v3));
            tau = seed_tau(mv, l);
            tf = tau;
        }
        bool q0 = v0 <= tf, q1 = v1 <= tf, q2 = v2 <= tf, q3 = v3 <= tf;
        unsigned long long anyb = __ballot(q0 | q1 | q2 | q3);
        if (!anyb) continue;
#pragma unroll
        for (int qq = 0; qq < 4; ++qq) {
            float vq = (qq == 0) ? v0 : (qq == 1) ? v1 : (qq == 2) ? v2 : v3;
            unsigned long long bal = __ballot((qq == 0) ? q0 : (qq == 1) ? q1 : (qq == 2) ? q2 : q3);
            while (bal) {
                int ln = __ffsll((unsigned long long)bal) - 1;
                bal &= bal - 1;
                float cv = __shfl(vq, ln);
                int cj = j0 + 4 * ln + qq;
                if (cv < d19 || (cv == d19 && cj < i19)) {
                    bool cmp = (dl < cv) || (dl == cv && il < cj);
                    unsigned long long cb = __ballot(cmp) & 0xFFFFFull;
                    int r = __popcll(cb);
                    float sdl = __shfl_up(dl, 1);
                    int sil = __shfl_up(il, 1);
                    if (l == r) { dl = cv; il = cj; }
                    else if (l > r && l < KNN) { dl = sdl; il = sil; }
                    d19 = __shfl(dl, 19); i19 = __shfl(il, 19);
                    tf = fminf(tau, d19);
                }
            }
        }
    }
    if (l < KNN) nbrs[(size_t)p * KNN + l] = il;
}

// ---------------------------------------------------------------- edgeconv (factored, fp32 exact)
template<int C>
__global__ void prep_w_kernel(const float* __restrict__ w, const float* __restrict__ b,
                              float* __restrict__ WW, float* __restrict__ bb) {
    int t = blockIdx.x * blockDim.x + threadIdx.x;
    if (t < 128) bb[t] = (t < 64) ? b[t] : 0.f;
    if (t >= C * 128) return;
    int c = t >> 7, f = t & 127;
    WW[t] = (f < 64) ? (w[c * 64 + f] - w[(C + c) * 64 + f]) : w[(C + c) * 64 + (f - 64)];
}

template<int C, int ROWS>
__global__ __launch_bounds__(128) void ec_gemm_kernel(
    const float* __restrict__ x, const float* __restrict__ WW,
    const float* __restrict__ bb, float* __restrict__ AB, int N) {
    __shared__ float Ws[C * 128];
    __shared__ float xs[ROWS * C];
    const int tid = threadIdx.x;
    const int r0 = blockIdx.x * ROWS;
    for (int idx = tid; idx < C * 32; idx += 128)
        reinterpret_cast<float4*>(Ws)[idx] = reinterpret_cast<const float4*>(WW)[idx];
    for (int idx = tid; idx < ROWS * C / 4; idx += 128)
        reinterpret_cast<float4*>(xs)[idx] =
            reinterpret_cast<const float4*>(x + (size_t)r0 * C)[idx];
    __syncthreads();
    const float bias = bb[tid];
#pragma unroll 1
    for (int r = 0; r < ROWS; ++r) {
        float acc = bias;
#pragma unroll
        for (int c = 0; c < C; ++c) acc = fmaf(xs[r * C + c], Ws[c * 128 + tid], acc);
        AB[(size_t)(r0 + r) * 128 + tid] = acc;
    }
}

__global__ __launch_bounds__(256) void ec_max_kernel(
    const float* __restrict__ AB, const int* __restrict__ nbrs,
    float* __restrict__ out, int N) {
    const int tid = threadIdx.x;
    const int w = tid >> 6, f = tid & 63;
    const int i = blockIdx.x * 4 + w;
    const float a = AB[(size_t)i * 128 + f];
    const int* nb = nbrs + (size_t)i * KNN;
    float m = -3.4e38f;
#pragma unroll
    for (int j = 0; j < KNN; ++j) {
        int n = nb[j];
        m = fmaxf(m, AB[(size_t)n * 128 + 64 + f]);
    }
    out[(size_t)i * 64 + f] = fmaxf(a + m, 0.f);
}

// ---------------------------------------------------------------- concat + split to bf16 hi/lo
__global__ void concat_split_kernel(const float* __restrict__ a, const float* __restrict__ b,
                                    const float* __restrict__ c,
                                    unsigned short* __restrict__ hi, unsigned short* __restrict__ lo,
                                    int N) {
    int t = blockIdx.x * blockDim.x + threadIdx.x;
    if (t >= N * 192) return;
    int r = t / 192, cc = t % 192;
    float v;
    if (cc < 64) v = a[(size_t)r * 64 + cc];
    else if (cc < 128) v = b[(size_t)r * 64 + cc - 64];
    else v = c[(size_t)r * 64 + cc - 128];
    unsigned short h = f2bf(v);
    hi[t] = h;
    lo[t] = f2bf(v - bf2f(h));
}

// ---------------------------------------------------------------- weight split: BT[F][3K]
__global__ void prep_bsplit_kernel(const float* __restrict__ W, unsigned short* __restrict__ BT,
                                   int K, int F) {
    int t = blockIdx.x * 256 + threadIdx.x;
    int K3 = 3 * K;
    if (t >= F * K3) return;
    int n = t / K3, kp = t - n * K3;
    int seg = kp / K;
    int k = kp - seg * K;
    float v = W[(size_t)k * F + n];
    unsigned short h = f2bf(v);
    BT[t] = (seg == 1) ? f2bf(v - bf2f(h)) : h;
}

// ---------------------------------------------------------------- split-bf16 MFMA GEMM
template<int BM, int BN, int SPLIT>
__global__ __launch_bounds__(256) void mfma_gemm_kernel(
    const unsigned short* __restrict__ Ahi, const unsigned short* __restrict__ Alo,
    const unsigned short* __restrict__ BT, const float* __restrict__ bias,
    float* __restrict__ Cf, unsigned short* __restrict__ Chi, unsigned short* __restrict__ Clo,
    int M, int N, int K) {
    constexpr int WR = BM / 64, WC = BN / 64;
    static_assert(WR * WC == 4, "4 waves");
    __shared__ __align__(16) unsigned short As[BM * 64];
    __shared__ __align__(16) unsigned short Bs[BN * 64];
    const int tid = threadIdx.x;
    const int w = tid >> 6, l = tid & 63;
    const int wr = w % WR, wc = w / WR;
    const int m0 = blockIdx.y * BM, n0 = blockIdx.x * BN;
    const int K3 = 3 * K;

    f32x4_t acc[4][4];
#pragma unroll
    for (int a = 0; a < 4; ++a)
#pragma unroll
        for (int b = 0; b < 4; ++b) acc[a][b] = (f32x4_t){0.f, 0.f, 0.f, 0.f};

    const int lr = l >> 3;
    const int swz = ((l & 7) ^ lr) * 8;
    const int frow = l & 15;
    const int fq = l >> 4;
    const int fswz = l & 7;

    for (int kt = 0; kt < K3 / 64; ++kt) {
        const int kk = kt * 64;
        const unsigned short* srcA; int k0;
        if (kk < K)            { srcA = Ahi; k0 = kk; }
        else if (kk < 2 * K)   { srcA = Ahi; k0 = kk - K; }
        else                   { srcA = Alo; k0 = kk - 2 * K; }
#pragma unroll
        for (int t = 0; t < BM / 32; ++t) {
            int row = w * (BM / 4) + t * 8;
            gload_lds16(srcA + (size_t)(m0 + row + lr) * K + k0 + swz,
                        (void*)(As + row * 64));
        }
#pragma unroll
        for (int t = 0; t < BN / 32; ++t) {
            int row = w * (BN / 4) + t * 8;
            gload_lds16(BT + (size_t)(n0 + row + lr) * K3 + kk + swz,
                        (void*)(Bs + row * 64));
        }
        __syncthreads();
#pragma unroll
        for (int ks = 0; ks < 2; ++ks) {
            bf16x8_t af[4], bf[4];
            const int o = (ks * 4 + fq) ^ fswz;
#pragma unroll
            for (int tm = 0; tm < 4; ++tm) {
                int row = wr * 64 + tm * 16 + frow;
                af[tm] = *reinterpret_cast<const bf16x8_t*>(As + row * 64 + o * 8);
            }
#pragma unroll
            for (int tn = 0; tn < 4; ++tn) {
                int row = wc * 64 + tn * 16 + frow;
                bf[tn] = *reinterpret_cast<const bf16x8_t*>(Bs + row * 64 + o * 8);
            }
#pragma unroll
            for (int tm = 0; tm < 4; ++tm)
#pragma unroll
                for (int tn = 0; tn < 4; ++tn)
                    acc[tm][tn] = __builtin_amdgcn_mfma_f32_16x16x32_bf16(
                        af[tm], bf[tn], acc[tm][tn], 0, 0, 0);
        }
        __syncthreads();
    }

#pragma unroll
    for (int tn = 0; tn < 4; ++tn) {
        int col = n0 + wc * 64 + tn * 16 + (l & 15);
        float bv = bias[col];
#pragma unroll
        for (int tm = 0; tm < 4; ++tm) {
#pragma unroll
            for (int r = 0; r < 4; ++r) {
                int row = m0 + wr * 64 + tm * 16 + (l >> 4) * 4 + r;
                float v = fmaxf(acc[tm][tn][r] + bv, 0.f);
                if constexpr (SPLIT) {
                    unsigned short h = f2bf(v);
                    Chi[(size_t)row * N + col] = h;
                    Clo[(size_t)row * N + col] = f2bf(v - bf2f(h));
                } else {
                    Cf[(size_t)row * N + col] = v;
                }
            }
        }
    }
}

// ---------------------------------------------------------------- last layer + log_softmax
__global__ __launch_bounds__(256) void last_layer_kernel(
    const float* __restrict__ A, const float* __restrict__ W,
    const float* __restrict__ b, float* __restrict__ out, int N) {
    constexpr int KD = 128, NC = 13;
    __shared__ float ws[KD * NC];
    __shared__ float bs[NC];
    const int tid = threadIdx.x;
    for (int idx = tid; idx < KD * NC; idx += 256) ws[idx] = W[idx];
    if (tid < NC) bs[tid] = b[tid];
    __syncthreads();
    int r = blockIdx.x * 256 + tid;
    if (r >= N) return;
    float acc[NC];
#pragma unroll
    for (int f = 0; f < NC; ++f) acc[f] = bs[f];
    const float4* row = reinterpret_cast<const float4*>(A + (size_t)r * KD);
#pragma unroll 4
    for (int c4 = 0; c4 < KD / 4; ++c4) {
        float4 v = row[c4];
#pragma unroll
        for (int f = 0; f < NC; ++f) acc[f] += v.x * ws[(c4 * 4 + 0) * NC + f];
#pragma unroll
        for (int f = 0; f < NC; ++f) acc[f] += v.y * ws[(c4 * 4 + 1) * NC + f];
#pragma unroll
        for (int f = 0; f < NC; ++f) acc[f] += v.z * ws[(c4 * 4 + 2) * NC + f];
#pragma unroll
        for (int f = 0; f < NC; ++f) acc[f] += v.w * ws[(c4 * 4 + 3) * NC + f];
    }
    float m = acc[0];
#pragma unroll
    for (int f = 1; f < NC; ++f) m = fmaxf(m, acc[f]);
    float s = 0.f;
#pragma unroll
    for (int f = 0; f < NC; ++f) s += expf(acc[f] - m);
    float ls = logf(s);
#pragma unroll
    for (int f = 0; f < NC; ++f) out[(size_t)r * NC + f] = acc[f] - m - ls;
}

// ---------------------------------------------------------------- launch
extern "C" void kernel_launch(void* const* d_in, const int* in_sizes, int n_in,
                              void* d_out, int out_size, void* d_ws, size_t ws_size,
                              hipStream_t stream) {
    const float* x   = (const float*)d_in[0];
    const float* w1  = (const float*)d_in[1];
    const float* b1  = (const float*)d_in[2];
    const float* w2  = (const float*)d_in[3];
    const float* b2  = (const float*)d_in[4];
    const float* w3  = (const float*)d_in[5];
    const float* b3  = (const float*)d_in[6];
    const float* wl1 = (const float*)d_in[7];
    const float* bl1 = (const float*)d_in[8];
    const float* wm1 = (const float*)d_in[9];
    const float* bm1 = (const float*)d_in[10];
    const float* wm2 = (const float*)d_in[11];
    const float* bm2 = (const float*)d_in[12];
    const float* wm3 = (const float*)d_in[13];
    const float* bm3 = (const float*)d_in[14];
    float* out = (float*)d_out;

    const int N = in_sizes[0] / 3;  // 8192
    const int NCH = N / CHSZ;       // 4 chunks

    float* ws = (float*)d_ws;
    size_t off = 0;
    auto alloc = [&](size_t n) { float* p = ws + off; off += n; return p; };
    float* sq  = alloc(N);
    int*   nbr = (int*)alloc((size_t)N * KNN);
    float* x1  = alloc((size_t)N * 64);
    float* x2  = alloc((size_t)N * 64);
    float* x3  = alloc((size_t)N * 64);
    float* AB  = alloc((size_t)N * 128);
    float* WW  = alloc(64 * 128);
    float* bb  = alloc(128);
    float* sd  = alloc((size_t)N * KNN);
    int*   si  = (int*)alloc((size_t)N * KNN);
    unsigned short* bt1 = (unsigned short*)alloc((size_t)1024 * 576 / 2);   // [1024][576]
    unsigned short* bt2 = (unsigned short*)alloc((size_t)256 * 3072 / 2);   // [256][3072]
    unsigned short* bt3 = (unsigned short*)alloc((size_t)128 * 768 / 2);    // [128][768]
    // union region: D chunk (knn phase) vs head activations (head phase)
    size_t dsz = (size_t)N * CHSZ;  // 16.8M floats > head usage (13.1M)
    float* Z = alloc(dsz);
    float* D = Z;
    unsigned short* cat_hi = (unsigned short*)Z;
    unsigned short* cat_lo = cat_hi + (size_t)N * 192;
    unsigned short* a1_hi  = cat_lo + (size_t)N * 192;
    unsigned short* a1_lo  = a1_hi + (size_t)N * 1024;
    unsigned short* a2_hi  = a1_lo + (size_t)N * 1024;
    unsigned short* a2_lo  = a2_hi + (size_t)N * 256;
    float* a3 = (float*)(a2_lo + (size_t)N * 256);

    // ---- stage 1 (C=3): fused dist+select, single dispatch
    rowsq_kernel<3><<<N / 256, 256, 0, stream>>>(x, sq, N);
    knn3_fused_kernel<<<N / 4, 256, 0, stream>>>(x, sq, nbr, N);
    prep_w_kernel<3><<<2, 256, 0, stream>>>(w1, b1, WW, bb);
    ec_gemm_kernel<3, 8><<<N / 8, 128, 0, stream>>>(x, WW, bb, AB, N);
    ec_max_kernel<<<N / 4, 256, 0, stream>>>(AB, nbr, x1, N);
    // ---- stage 2 (C=64)
    rowsq_kernel<64><<<N / 256, 256, 0, stream>>>(x1, sq, N);
    for (int c = 0; c < NCH; ++c) {
        dist_gemm_kernel<<<dim3(CHSZ / 128, N / 128), 256, 0, stream>>>(x1, sq, D, N, c * CHSZ);
        knn_select_kernel<<<N / 4, 256, 0, stream>>>(D, sd, si, nbr, c * CHSZ, c == 0, c == NCH - 1);
    }
    prep_w_kernel<64><<<32, 256, 0, stream>>>(w2, b2, WW, bb);
    ec_gemm_kernel<64, 8><<<N / 8, 128, 0, stream>>>(x1, WW, bb, AB, N);
    ec_max_kernel<<<N / 4, 256, 0, stream>>>(AB, nbr, x2, N);
    // ---- stage 3 (C=64)
    rowsq_kernel<64><<<N / 256, 256, 0, stream>>>(x2, sq, N);
    for (int c = 0; c < NCH; ++c) {
        dist_gemm_kernel<<<dim3(CHSZ / 128, N / 128), 256, 0, stream>>>(x2, sq, D, N, c * CHSZ);
        knn_select_kernel<<<N / 4, 256, 0, stream>>>(D, sd, si, nbr, c * CHSZ, c == 0, c == NCH - 1);
    }
    prep_w_kernel<64><<<32, 256, 0, stream>>>(w3, b3, WW, bb);
    ec_gemm_kernel<64, 8><<<N / 8, 128, 0, stream>>>(x2, WW, bb, AB, N);
    ec_max_kernel<<<N / 4, 256, 0, stream>>>(AB, nbr, x3, N);
    // ---- MLP head (split-bf16 MFMA)
    prep_bsplit_kernel<<<(1024 * 576 + 255) / 256, 256, 0, stream>>>(wl1, bt1, 192, 1024);
    prep_bsplit_kernel<<<(256 * 3072 + 255) / 256, 256, 0, stream>>>(wm1, bt2, 1024, 256);
    prep_bsplit_kernel<<<(128 * 768 + 255) / 256, 256, 0, stream>>>(wm2, bt3, 256, 128);
    concat_split_kernel<<<(N * 192 + 255) / 256, 256, 0, stream>>>(x1, x2, x3, cat_hi, cat_lo, N);
    mfma_gemm_kernel<128, 128, 1><<<dim3(1024 / 128, N / 128), 256, 0, stream>>>(
        cat_hi, cat_lo, bt1, bl1, nullptr, a1_hi, a1_lo, N, 1024, 192);
    mfma_gemm_kernel<256, 64, 1><<<dim3(256 / 64, N / 256), 256, 0, stream>>>(
        a1_hi, a1_lo, bt2, bm1, nullptr, a2_hi, a2_lo, N, 256, 1024);
    mfma_gemm_kernel<256, 64, 0><<<dim3(128 / 64, N / 256), 256, 0, stream>>>(
        a2_hi, a2_lo, bt3, bm2, a3, nullptr, nullptr, N, 128, 256);
    last_layer_kernel<<<(N + 255) / 256, 256, 0, stream>>>(a3, wm3, bm3, out, N);
}

// Round 7
// 737.233 us; speedup vs baseline: 7.6115x; 1.0382x over previous
//
#include <hip/hip_runtime.h>
#include <hip/hip_bf16.h>
#include <math.h>

#define KNN 20
#define CHSZ 2048   // candidate chunk size for distance matrix

typedef __attribute__((ext_vector_type(8))) short bf16x8_t;
typedef __attribute__((ext_vector_type(4))) float f32x4_t;

// bf16 split helpers (RNE)
__device__ __forceinline__ unsigned short f2bf(float f) {
    unsigned u = __float_as_uint(f);
    u += 0x7fffu + ((u >> 16) & 1u);
    return (unsigned short)(u >> 16);
}
__device__ __forceinline__ float bf2f(unsigned short h) {
    return __uint_as_float((unsigned)h << 16);
}

// async global->LDS, 16 B per lane; dest = wave-uniform base + lane*16
__device__ __forceinline__ void gload_lds16(const void* g, void* l) {
    auto gp = reinterpret_cast<const __attribute__((address_space(1))) unsigned*>(
        reinterpret_cast<uintptr_t>(g));
    auto lp = reinterpret_cast<__attribute__((address_space(3))) unsigned*>(
        reinterpret_cast<uintptr_t>(l));
    __builtin_amdgcn_global_load_lds(gp, lp, 16, 0, 0);
}

// 64-lane bitonic ascending sort of one float per lane; returns lane-19 value.
// Seeds the top-20 filter threshold: 20th order statistic of the 64 lane
// minima is >= the full set's 20th -> valid (never rejects a final top-20).
__device__ __forceinline__ float seed_tau(float mv, int l) {
#pragma unroll
    for (int k = 2; k <= 64; k <<= 1) {
#pragma unroll
        for (int j = k >> 1; j > 0; j >>= 1) {
            float o = __shfl_xor(mv, j);
            bool keepMin = (((l & j) == 0) == ((l & k) == 0));
            mv = keepMin ? fminf(mv, o) : fmaxf(mv, o);
        }
    }
    return __shfl(mv, 19);
}

// ---------------------------------------------------------------- rowsq
template<int C>
__global__ void rowsq_kernel(const float* __restrict__ x, float* __restrict__ sq, int N) {
    int i = blockIdx.x * blockDim.x + threadIdx.x;
    if (i >= N) return;
    float s = 0.f;
    if constexpr (C == 64) {
        const float4* p = reinterpret_cast<const float4*>(x + (size_t)i * C);
#pragma unroll
        for (int c = 0; c < 16; ++c) {
            float4 v = p[c];
            s += v.x * v.x + v.y * v.y + v.z * v.z + v.w * v.w;
        }
    } else {
#pragma unroll
        for (int c = 0; c < C; ++c) { float v = x[(size_t)i * C + c]; s += v * v; }
    }
    sq[i] = s;
}

// ---------------------------------------------------------------- triple-bf16 split
// fp32 = h + l + m (exactly, 3x8 significand bits). Xs[row][0:64)=h,
// [64:128)=l, [128:192)=m.
__global__ void xsplit3_kernel(const float* __restrict__ X,
                               unsigned short* __restrict__ Xs, int N) {
    int t = blockIdx.x * 256 + threadIdx.x;
    if (t >= N * 64) return;
    int r = t >> 6, c = t & 63;
    float v = X[t];
    unsigned short h = f2bf(v);
    float r1 = v - bf2f(h);
    unsigned short lo = f2bf(r1);
    float r2 = r1 - bf2f(lo);
    unsigned short mm = f2bf(r2);
    Xs[(size_t)r * 192 + c] = h;
    Xs[(size_t)r * 192 + 64 + c] = lo;
    Xs[(size_t)r * 192 + 128 + c] = mm;
}

// ---------------------------------------------------------------- dist MFMA (C=64)
// D[m][n] = sq[m] + sq[j] - 2 * dot(X[m], X[j]) with dot computed by 6-term
// split-bf16 MFMA (hh, hl, lh, ll, hm, mh; dropped terms <= 2^-25 rel) --
// fp32-ulp-level accuracy, same error class as reordered fp32.
// 128x128 tile, 2x2 waves of 64x64, 16x16x32 bf16 MFMA, 6 passes of K=64.
__global__ __launch_bounds__(256) void dist_mfma_kernel(
    const unsigned short* __restrict__ Xs, const float* __restrict__ sq,
    float* __restrict__ D, int chunk_base) {
    __shared__ __align__(16) unsigned short As[128 * 64];
    __shared__ __align__(16) unsigned short Bs[128 * 64];
    const int tid = threadIdx.x;
    const int w = tid >> 6, l = tid & 63;
    const int wr = w & 1, wc = w >> 1;
    const int m0 = blockIdx.y * 128;
    const int n0 = blockIdx.x * 128;          // chunk-local
    const int jb = chunk_base + n0;           // global candidate base
    const int lr = l >> 3;
    const int swz = ((l & 7) ^ lr) * 8;
    const int frow = l & 15;
    const int fq = l >> 4;
    const int fswz = l & 7;

    f32x4_t acc[4][4];
#pragma unroll
    for (int a = 0; a < 4; ++a)
#pragma unroll
        for (int b = 0; b < 4; ++b) acc[a][b] = (f32x4_t){0.f, 0.f, 0.f, 0.f};

    const int segA[6] = {0, 0, 64, 64, 0, 128};
    const int segB[6] = {0, 64, 0, 64, 128, 0};

#pragma unroll 1
    for (int t6 = 0; t6 < 6; ++t6) {
        const int sA = segA[t6], sB = segB[t6];
#pragma unroll
        for (int s = 0; s < 4; ++s) {
            int row = w * 32 + s * 8;
            gload_lds16(Xs + (size_t)(m0 + row + lr) * 192 + sA + swz,
                        (void*)(As + row * 64));
        }
#pragma unroll
        for (int s = 0; s < 4; ++s) {
            int row = w * 32 + s * 8;
            gload_lds16(Xs + (size_t)(jb + row + lr) * 192 + sB + swz,
                        (void*)(Bs + row * 64));
        }
        __syncthreads();
#pragma unroll
        for (int ks = 0; ks < 2; ++ks) {
            bf16x8_t af[4], bf[4];
            const int o = (ks * 4 + fq) ^ fswz;
#pragma unroll
            for (int tm = 0; tm < 4; ++tm)
                af[tm] = *reinterpret_cast<const bf16x8_t*>(
                    As + (wr * 64 + tm * 16 + frow) * 64 + o * 8);
#pragma unroll
            for (int tn = 0; tn < 4; ++tn)
                bf[tn] = *reinterpret_cast<const bf16x8_t*>(
                    Bs + (wc * 64 + tn * 16 + frow) * 64 + o * 8);
#pragma unroll
            for (int tm = 0; tm < 4; ++tm)
#pragma unroll
                for (int tn = 0; tn < 4; ++tn)
                    acc[tm][tn] = __builtin_amdgcn_mfma_f32_16x16x32_bf16(
                        af[tm], bf[tn], acc[tm][tn], 0, 0, 0);
        }
        __syncthreads();
    }

    // epilogue: C/D layout col=lane&15, row=(lane>>4)*4+reg
    float sn[4]; int jn[4], nc[4];
#pragma unroll
    for (int tn = 0; tn < 4; ++tn) {
        nc[tn] = wc * 64 + tn * 16 + (l & 15);
        jn[tn] = jb + nc[tn];
        sn[tn] = sq[jn[tn]];
    }
#pragma unroll
    for (int tm = 0; tm < 4; ++tm) {
#pragma unroll
        for (int r = 0; r < 4; ++r) {
            int m = m0 + wr * 64 + tm * 16 + (l >> 4) * 4 + r;
            float sm = sq[m];
#pragma unroll
            for (int tn = 0; tn < 4; ++tn) {
                float val = sm + sn[tn] - 2.f * acc[tm][tn][r];
                if (m == jn[tn]) val = INFINITY;
                D[(size_t)m * CHSZ + n0 + nc[tn]] = val;
            }
        }
    }
}

// ---------------------------------------------------------------- knn select (C=64 path)
// One wave per point; distributed sorted top-20 (lanes 0..19), lex (d,idx)
// order == jax.lax.top_k tie-break. Loads pipelined upfront; coarse filter
// threshold seeded (first chunk) from tile-0 lane minima via bitonic.
__global__ __launch_bounds__(256) void knn_select_kernel(
    const float* __restrict__ D, float* __restrict__ sd, int* __restrict__ si,
    int* __restrict__ nbrs, int chunk_base, int first, int last) {
    const int tid = threadIdx.x;
    const int w = tid >> 6, l = tid & 63;
    const int p = blockIdx.x * 4 + w;

    float dl = INFINITY; int il = 0x7fffffff;
    if (!first && l < KNN) { dl = sd[(size_t)p * KNN + l]; il = si[(size_t)p * KNN + l]; }
    float d19 = __shfl(dl, 19); int i19 = __shfl(il, 19);

    const float4* Drow = reinterpret_cast<const float4*>(D + (size_t)p * CHSZ);
    float4 v[8];
#pragma unroll
    for (int b = 0; b < 8; ++b) v[b] = Drow[b * 64 + l];

    float tau = INFINITY;
    if (first) {
        float mv = fminf(fminf(v[0].x, v[0].y), fminf(v[0].z, v[0].w));
        tau = seed_tau(mv, l);
    }
    float tf = fminf(tau, d19);

#pragma unroll
    for (int b = 0; b < 8; ++b) {
        bool q0 = v[b].x <= tf, q1 = v[b].y <= tf, q2 = v[b].z <= tf, q3 = v[b].w <= tf;
        unsigned long long anyb = __ballot(q0 | q1 | q2 | q3);
        if (!anyb) continue;
#pragma unroll
        for (int qq = 0; qq < 4; ++qq) {
            float vq = (qq == 0) ? v[b].x : (qq == 1) ? v[b].y : (qq == 2) ? v[b].z : v[b].w;
            unsigned long long bal = __ballot((qq == 0) ? q0 : (qq == 1) ? q1 : (qq == 2) ? q2 : q3);
            while (bal) {
                int ln = __ffsll((unsigned long long)bal) - 1;
                bal &= bal - 1;
                float cv = __shfl(vq, ln);
                int cj = chunk_base + b * 256 + 4 * ln + qq;
                if (cv < d19 || (cv == d19 && cj < i19)) {
                    bool cmp = (dl < cv) || (dl == cv && il < cj);
                    unsigned long long cb = __ballot(cmp) & 0xFFFFFull;
                    int r = __popcll(cb);
                    float sdl = __shfl_up(dl, 1);
                    int sil = __shfl_up(il, 1);
                    if (l == r) { dl = cv; il = cj; }
                    else if (l > r && l < KNN) { dl = sdl; il = sil; }
                    d19 = __shfl(dl, 19); i19 = __shfl(il, 19);
                    tf = fminf(tau, d19);
                }
            }
        }
    }
    if (l < KNN) {
        sd[(size_t)p * KNN + l] = dl;
        si[(size_t)p * KNN + l] = il;
        if (last) nbrs[(size_t)p * KNN + l] = il;
    }
}

// ---------------------------------------------------------------- knn fused (C=3)
__global__ __launch_bounds__(256) void knn3_fused_kernel(
    const float* __restrict__ X, const float* __restrict__ sq,
    int* __restrict__ nbrs, int N) {
    const int tid = threadIdx.x;
    const int w = tid >> 6, l = tid & 63;
    const int p = blockIdx.x * 4 + w;
    const float x0 = X[(size_t)p * 3], x1 = X[(size_t)p * 3 + 1], x2 = X[(size_t)p * 3 + 2];
    const float sp = sq[p];
    float dl = INFINITY; int il = 0x7fffffff;
    float d19 = INFINITY; int i19 = 0x7fffffff;
    float tau = INFINITY, tf = INFINITY;

#pragma unroll 1
    for (int j0 = 0; j0 < N; j0 += 256) {
        const int jl = j0 + 4 * l;
        const float4* xr = reinterpret_cast<const float4*>(X + (size_t)jl * 3);
        float4 r0 = xr[0], r1 = xr[1], r2 = xr[2];
        float4 sj = *reinterpret_cast<const float4*>(sq + jl);
        float v0 = sp + sj.x - 2.f * (x0 * r0.x + x1 * r0.y + x2 * r0.z);
        float v1 = sp + sj.y - 2.f * (x0 * r0.w + x1 * r1.x + x2 * r1.y);
        float v2 = sp + sj.z - 2.f * (x0 * r1.z + x1 * r1.w + x2 * r2.x);
        float v3 = sp + sj.w - 2.f * (x0 * r2.y + x1 * r2.z + x2 * r2.w);
        if (jl + 0 == p) v0 = INFINITY;
        if (jl + 1 == p) v1 = INFINITY;
        if (jl + 2 == p) v2 = INFINITY;
        if (jl + 3 == p) v3 = INFINITY;
        if (j0 == 0) {
            float mv = fminf(fminf(v0, v1), fminf(v2, v3));
            tau = seed_tau(mv, l);
            tf = tau;
        }
        bool q0 = v0 <= tf, q1 = v1 <= tf, q2 = v2 <= tf, q3 = v3 <= tf;
        unsigned long long anyb = __ballot(q0 | q1 | q2 | q3);
        if (!anyb) continue;
#pragma unroll
        for (int qq = 0; qq < 4; ++qq) {
            float vq = (qq == 0) ? v0 : (qq == 1) ? v1 : (qq == 2) ? v2 : v3;
            unsigned long long bal = __ballot((qq == 0) ? q0 : (qq == 1) ? q1 : (qq == 2) ? q2 : q3);
            while (bal) {
                int ln = __ffsll((unsigned long long)bal) - 1;
                bal &= bal - 1;
                float cv = __shfl(vq, ln);
                int cj = j0 + 4 * ln + qq;
                if (cv < d19 || (cv == d19 && cj < i19)) {
                    bool cmp = (dl < cv) || (dl == cv && il < cj);
                    unsigned long long cb = __ballot(cmp) & 0xFFFFFull;
                    int r = __popcll(cb);
                    float sdl = __shfl_up(dl, 1);
                    int sil = __shfl_up(il, 1);
                    if (l == r) { dl = cv; il = cj; }
                    else if (l > r && l < KNN) { dl = sdl; il = sil; }
                    d19 = __shfl(dl, 19); i19 = __shfl(il, 19);
                    tf = fminf(tau, d19);
                }
            }
        }
    }
    if (l < KNN) nbrs[(size_t)p * KNN + l] = il;
}

// ---------------------------------------------------------------- edgeconv (factored, fp32 exact)
template<int C>
__global__ void prep_w_kernel(const float* __restrict__ w, const float* __restrict__ b,
                              float* __restrict__ WW, float* __restrict__ bb) {
    int t = blockIdx.x * blockDim.x + threadIdx.x;
    if (t < 128) bb[t] = (t < 64) ? b[t] : 0.f;
    if (t >= C * 128) return;
    int c = t >> 7, f = t & 127;
    WW[t] = (f < 64) ? (w[c * 64 + f] - w[(C + c) * 64 + f]) : w[(C + c) * 64 + (f - 64)];
}

template<int C, int ROWS>
__global__ __launch_bounds__(128) void ec_gemm_kernel(
    const float* __restrict__ x, const float* __restrict__ WW,
    const float* __restrict__ bb, float* __restrict__ AB, int N) {
    __shared__ float Ws[C * 128];
    __shared__ float xs[ROWS * C];
    const int tid = threadIdx.x;
    const int r0 = blockIdx.x * ROWS;
    for (int idx = tid; idx < C * 32; idx += 128)
        reinterpret_cast<float4*>(Ws)[idx] = reinterpret_cast<const float4*>(WW)[idx];
    for (int idx = tid; idx < ROWS * C / 4; idx += 128)
        reinterpret_cast<float4*>(xs)[idx] =
            reinterpret_cast<const float4*>(x + (size_t)r0 * C)[idx];
    __syncthreads();
    const float bias = bb[tid];
#pragma unroll 1
    for (int r = 0; r < ROWS; ++r) {
        float acc = bias;
#pragma unroll
        for (int c = 0; c < C; ++c) acc = fmaf(xs[r * C + c], Ws[c * 128 + tid], acc);
        AB[(size_t)(r0 + r) * 128 + tid] = acc;
    }
}

__global__ __launch_bounds__(256) void ec_max_kernel(
    const float* __restrict__ AB, const int* __restrict__ nbrs,
    float* __restrict__ out, int N) {
    const int tid = threadIdx.x;
    const int w = tid >> 6, f = tid & 63;
    const int i = blockIdx.x * 4 + w;
    const float a = AB[(size_t)i * 128 + f];
    const int* nb = nbrs + (size_t)i * KNN;
    float m = -3.4e38f;
#pragma unroll
    for (int j = 0; j < KNN; ++j) {
        int n = nb[j];
        m = fmaxf(m, AB[(size_t)n * 128 + 64 + f]);
    }
    out[(size_t)i * 64 + f] = fmaxf(a + m, 0.f);
}

// ---------------------------------------------------------------- concat + split to bf16 hi/lo
__global__ void concat_split_kernel(const float* __restrict__ a, const float* __restrict__ b,
                                    const float* __restrict__ c,
                                    unsigned short* __restrict__ hi, unsigned short* __restrict__ lo,
                                    int N) {
    int t = blockIdx.x * blockDim.x + threadIdx.x;
    if (t >= N * 192) return;
    int r = t / 192, cc = t % 192;
    float v;
    if (cc < 64) v = a[(size_t)r * 64 + cc];
    else if (cc < 128) v = b[(size_t)r * 64 + cc - 64];
    else v = c[(size_t)r * 64 + cc - 128];
    unsigned short h = f2bf(v);
    hi[t] = h;
    lo[t] = f2bf(v - bf2f(h));
}

// ---------------------------------------------------------------- weight split: BT[F][3K]
__global__ void prep_bsplit_kernel(const float* __restrict__ W, unsigned short* __restrict__ BT,
                                   int K, int F) {
    int t = blockIdx.x * 256 + threadIdx.x;
    int K3 = 3 * K;
    if (t >= F * K3) return;
    int n = t / K3, kp = t - n * K3;
    int seg = kp / K;
    int k = kp - seg * K;
    float v = W[(size_t)k * F + n];
    unsigned short h = f2bf(v);
    BT[t] = (seg == 1) ? f2bf(v - bf2f(h)) : h;
}

// ---------------------------------------------------------------- split-bf16 MFMA GEMM
template<int BM, int BN, int SPLIT>
__global__ __launch_bounds__(256) void mfma_gemm_kernel(
    const unsigned short* __restrict__ Ahi, const unsigned short* __restrict__ Alo,
    const unsigned short* __restrict__ BT, const float* __restrict__ bias,
    float* __restrict__ Cf, unsigned short* __restrict__ Chi, unsigned short* __restrict__ Clo,
    int M, int N, int K) {
    constexpr int WR = BM / 64, WC = BN / 64;
    static_assert(WR * WC == 4, "4 waves");
    __shared__ __align__(16) unsigned short As[BM * 64];
    __shared__ __align__(16) unsigned short Bs[BN * 64];
    const int tid = threadIdx.x;
    const int w = tid >> 6, l = tid & 63;
    const int wr = w % WR, wc = w / WR;
    const int m0 = blockIdx.y * BM, n0 = blockIdx.x * BN;
    const int K3 = 3 * K;

    f32x4_t acc[4][4];
#pragma unroll
    for (int a = 0; a < 4; ++a)
#pragma unroll
        for (int b = 0; b < 4; ++b) acc[a][b] = (f32x4_t){0.f, 0.f, 0.f, 0.f};

    const int lr = l >> 3;
    const int swz = ((l & 7) ^ lr) * 8;
    const int frow = l & 15;
    const int fq = l >> 4;
    const int fswz = l & 7;

    for (int kt = 0; kt < K3 / 64; ++kt) {
        const int kk = kt * 64;
        const unsigned short* srcA; int k0;
        if (kk < K)            { srcA = Ahi; k0 = kk; }
        else if (kk < 2 * K)   { srcA = Ahi; k0 = kk - K; }
        else                   { srcA = Alo; k0 = kk - 2 * K; }
#pragma unroll
        for (int t = 0; t < BM / 32; ++t) {
            int row = w * (BM / 4) + t * 8;
            gload_lds16(srcA + (size_t)(m0 + row + lr) * K + k0 + swz,
                        (void*)(As + row * 64));
        }
#pragma unroll
        for (int t = 0; t < BN / 32; ++t) {
            int row = w * (BN / 4) + t * 8;
            gload_lds16(BT + (size_t)(n0 + row + lr) * K3 + kk + swz,
                        (void*)(Bs + row * 64));
        }
        __syncthreads();
#pragma unroll
        for (int ks = 0; ks < 2; ++ks) {
            bf16x8_t af[4], bf[4];
            const int o = (ks * 4 + fq) ^ fswz;
#pragma unroll
            for (int tm = 0; tm < 4; ++tm) {
                int row = wr * 64 + tm * 16 + frow;
                af[tm] = *reinterpret_cast<const bf16x8_t*>(As + row * 64 + o * 8);
            }
#pragma unroll
            for (int tn = 0; tn < 4; ++tn) {
                int row = wc * 64 + tn * 16 + frow;
                bf[tn] = *reinterpret_cast<const bf16x8_t*>(Bs + row * 64 + o * 8);
            }
#pragma unroll
            for (int tm = 0; tm < 4; ++tm)
#pragma unroll
                for (int tn = 0; tn < 4; ++tn)
                    acc[tm][tn] = __builtin_amdgcn_mfma_f32_16x16x32_bf16(
                        af[tm], bf[tn], acc[tm][tn], 0, 0, 0);
        }
        __syncthreads();
    }

#pragma unroll
    for (int tn = 0; tn < 4; ++tn) {
        int col = n0 + wc * 64 + tn * 16 + (l & 15);
        float bv = bias[col];
#pragma unroll
        for (int tm = 0; tm < 4; ++tm) {
#pragma unroll
            for (int r = 0; r < 4; ++r) {
                int row = m0 + wr * 64 + tm * 16 + (l >> 4) * 4 + r;
                float v = fmaxf(acc[tm][tn][r] + bv, 0.f);
                if constexpr (SPLIT) {
                    unsigned short h = f2bf(v);
                    Chi[(size_t)row * N + col] = h;
                    Clo[(size_t)row * N + col] = f2bf(v - bf2f(h));
                } else {
                    Cf[(size_t)row * N + col] = v;
                }
            }
        }
    }
}

// ---------------------------------------------------------------- last layer + log_softmax
__global__ __launch_bounds__(256) void last_layer_kernel(
    const float* __restrict__ A, const float* __restrict__ W,
    const float* __restrict__ b, float* __restrict__ out, int N) {
    constexpr int KD = 128, NC = 13;
    __shared__ float ws[KD * NC];
    __shared__ float bs[NC];
    const int tid = threadIdx.x;
    for (int idx = tid; idx < KD * NC; idx += 256) ws[idx] = W[idx];
    if (tid < NC) bs[tid] = b[tid];
    __syncthreads();
    int r = blockIdx.x * 256 + tid;
    if (r >= N) return;
    float acc[NC];
#pragma unroll
    for (int f = 0; f < NC; ++f) acc[f] = bs[f];
    const float4* row = reinterpret_cast<const float4*>(A + (size_t)r * KD);
#pragma unroll 4
    for (int c4 = 0; c4 < KD / 4; ++c4) {
        float4 v = row[c4];
#pragma unroll
        for (int f = 0; f < NC; ++f) acc[f] += v.x * ws[(c4 * 4 + 0) * NC + f];
#pragma unroll
        for (int f = 0; f < NC; ++f) acc[f] += v.y * ws[(c4 * 4 + 1) * NC + f];
#pragma unroll
        for (int f = 0; f < NC; ++f) acc[f] += v.z * ws[(c4 * 4 + 2) * NC + f];
#pragma unroll
        for (int f = 0; f < NC; ++f) acc[f] += v.w * ws[(c4 * 4 + 3) * NC + f];
    }
    float m = acc[0];
#pragma unroll
    for (int f = 1; f < NC; ++f) m = fmaxf(m, acc[f]);
    float s = 0.f;
#pragma unroll
    for (int f = 0; f < NC; ++f) s += expf(acc[f] - m);
    float ls = logf(s);
#pragma unroll
    for (int f = 0; f < NC; ++f) out[(size_t)r * NC + f] = acc[f] - m - ls;
}

// ---------------------------------------------------------------- launch
extern "C" void kernel_launch(void* const* d_in, const int* in_sizes, int n_in,
                              void* d_out, int out_size, void* d_ws, size_t ws_size,
                              hipStream_t stream) {
    const float* x   = (const float*)d_in[0];
    const float* w1  = (const float*)d_in[1];
    const float* b1  = (const float*)d_in[2];
    const float* w2  = (const float*)d_in[3];
    const float* b2  = (const float*)d_in[4];
    const float* w3  = (const float*)d_in[5];
    const float* b3  = (const float*)d_in[6];
    const float* wl1 = (const float*)d_in[7];
    const float* bl1 = (const float*)d_in[8];
    const float* wm1 = (const float*)d_in[9];
    const float* bm1 = (const float*)d_in[10];
    const float* wm2 = (const float*)d_in[11];
    const float* bm2 = (const float*)d_in[12];
    const float* wm3 = (const float*)d_in[13];
    const float* bm3 = (const float*)d_in[14];
    float* out = (float*)d_out;

    const int N = in_sizes[0] / 3;  // 8192
    const int NCH = N / CHSZ;       // 4 chunks

    float* ws = (float*)d_ws;
    size_t off = 0;
    auto alloc = [&](size_t n) { float* p = ws + off; off += n; return p; };
    float* sq  = alloc(N);
    int*   nbr = (int*)alloc((size_t)N * KNN);
    float* x1  = alloc((size_t)N * 64);
    float* x2  = alloc((size_t)N * 64);
    float* x3  = alloc((size_t)N * 64);
    float* AB  = alloc((size_t)N * 128);
    float* WW  = alloc(64 * 128);
    float* bb  = alloc(128);
    float* sd  = alloc((size_t)N * KNN);
    int*   si  = (int*)alloc((size_t)N * KNN);
    unsigned short* Xs = (unsigned short*)alloc((size_t)N * 192 / 2);       // triple-split [N][192]
    unsigned short* bt1 = (unsigned short*)alloc((size_t)1024 * 576 / 2);   // [1024][576]
    unsigned short* bt2 = (unsigned short*)alloc((size_t)256 * 3072 / 2);   // [256][3072]
    unsigned short* bt3 = (unsigned short*)alloc((size_t)128 * 768 / 2);    // [128][768]
    // union region: D chunk (knn phase) vs head activations (head phase)
    size_t dsz = (size_t)N * CHSZ;  // 16.8M floats > head usage (13.1M)
    float* Z = alloc(dsz);
    float* D = Z;
    unsigned short* cat_hi = (unsigned short*)Z;
    unsigned short* cat_lo = cat_hi + (size_t)N * 192;
    unsigned short* a1_hi  = cat_lo + (size_t)N * 192;
    unsigned short* a1_lo  = a1_hi + (size_t)N * 1024;
    unsigned short* a2_hi  = a1_lo + (size_t)N * 1024;
    unsigned short* a2_lo  = a2_hi + (size_t)N * 256;
    float* a3 = (float*)(a2_lo + (size_t)N * 256);

    // ---- stage 1 (C=3): fused dist+select, single dispatch
    rowsq_kernel<3><<<N / 256, 256, 0, stream>>>(x, sq, N);
    knn3_fused_kernel<<<N / 4, 256, 0, stream>>>(x, sq, nbr, N);
    prep_w_kernel<3><<<2, 256, 0, stream>>>(w1, b1, WW, bb);
    ec_gemm_kernel<3, 8><<<N / 8, 128, 0, stream>>>(x, WW, bb, AB, N);
    ec_max_kernel<<<N / 4, 256, 0, stream>>>(AB, nbr, x1, N);
    // ---- stage 2 (C=64): MFMA distance via exact triple-bf16 split
    rowsq_kernel<64><<<N / 256, 256, 0, stream>>>(x1, sq, N);
    xsplit3_kernel<<<(N * 64 + 255) / 256, 256, 0, stream>>>(x1, Xs, N);
    for (int c = 0; c < NCH; ++c) {
        dist_mfma_kernel<<<dim3(CHSZ / 128, N / 128), 256, 0, stream>>>(Xs, sq, D, c * CHSZ);
        knn_select_kernel<<<N / 4, 256, 0, stream>>>(D, sd, si, nbr, c * CHSZ, c == 0, c == NCH - 1);
    }
    prep_w_kernel<64><<<32, 256, 0, stream>>>(w2, b2, WW, bb);
    ec_gemm_kernel<64, 8><<<N / 8, 128, 0, stream>>>(x1, WW, bb, AB, N);
    ec_max_kernel<<<N / 4, 256, 0, stream>>>(AB, nbr, x2, N);
    // ---- stage 3 (C=64)
    rowsq_kernel<64><<<N / 256, 256, 0, stream>>>(x2, sq, N);
    xsplit3_kernel<<<(N * 64 + 255) / 256, 256, 0, stream>>>(x2, Xs, N);
    for (int c = 0; c < NCH; ++c) {
        dist_mfma_kernel<<<dim3(CHSZ / 128, N / 128), 256, 0, stream>>>(Xs, sq, D, c * CHSZ);
        knn_select_kernel<<<N / 4, 256, 0, stream>>>(D, sd, si, nbr, c * CHSZ, c == 0, c == NCH - 1);
    }
    prep_w_kernel<64><<<32, 256, 0, stream>>>(w3, b3, WW, bb);
    ec_gemm_kernel<64, 8><<<N / 8, 128, 0, stream>>>(x2, WW, bb, AB, N);
    ec_max_kernel<<<N / 4, 256, 0, stream>>>(AB, nbr, x3, N);
    // ---- MLP head (split-bf16 MFMA)
    prep_bsplit_kernel<<<(1024 * 576 + 255) / 256, 256, 0, stream>>>(wl1, bt1, 192, 1024);
    prep_bsplit_kernel<<<(256 * 3072 + 255) / 256, 256, 0, stream>>>(wm1, bt2, 1024, 256);
    prep_bsplit_kernel<<<(128 * 768 + 255) / 256, 256, 0, stream>>>(wm2, bt3, 256, 128);
    concat_split_kernel<<<(N * 192 + 255) / 256, 256, 0, stream>>>(x1, x2, x3, cat_hi, cat_lo, N);
    mfma_gemm_kernel<128, 128, 1><<<dim3(1024 / 128, N / 128), 256, 0, stream>>>(
        cat_hi, cat_lo, bt1, bl1, nullptr, a1_hi, a1_lo, N, 1024, 192);
    mfma_gemm_kernel<256, 64, 1><<<dim3(256 / 64, N / 256), 256, 0, stream>>>(
        a1_hi, a1_lo, bt2, bm1, nullptr, a2_hi, a2_lo, N, 256, 1024);
    mfma_gemm_kernel<256, 64, 0><<<dim3(128 / 64, N / 256), 256, 0, stream>>>(
        a2_hi, a2_lo, bt3, bm2, a3, nullptr, nullptr, N, 128, 256);
    last_layer_kernel<<<(N + 255) / 256, 256, 0, stream>>>(a3, wm3, bm3, out, N);
}